// Round 8
// baseline (279.863 us; speedup 1.0000x reference)
//
#include <hip/hip_runtime.h>
#include <math.h>

#define M_TOK 25600   // 25 images * 1024 tokens

typedef __attribute__((ext_vector_type(8))) short bf16x8;
typedef __attribute__((ext_vector_type(4))) float f32x4;
typedef __attribute__((ext_vector_type(4))) int   i32x4;
typedef __attribute__((ext_vector_type(2))) int   i32x2;

__device__ __forceinline__ unsigned short f2b(float x) {
    unsigned u = __builtin_bit_cast(unsigned, x);
    return (unsigned short)((u + 0x7fffu + ((u >> 16) & 1u)) >> 16);
}
__device__ __forceinline__ float b2f(unsigned short h) {
    unsigned u = ((unsigned)h) << 16;
    return __builtin_bit_cast(float, u);
}
__device__ __forceinline__ unsigned cvtpk(float lo, float hi) {
    unsigned r;
    asm("v_cvt_pk_bf16_f32 %0, %1, %2" : "=v"(r) : "v"(lo), "v"(hi));
    return r;
}

// ---------------------------------------------------------------------------
// Weight fp32->bf16 conversion (round-5 version, verbatim)
// ---------------------------------------------------------------------------
__global__ __launch_bounds__(256) void cvtw_k(const float* __restrict__ s0, const float* __restrict__ s1,
                                              const float* __restrict__ s2, const float* __restrict__ s3,
                                              const float* __restrict__ s4, const float* __restrict__ s5,
                                              short* __restrict__ dst) {
    int i = blockIdx.x * 256 + threadIdx.x;      // < 286208
    if (i < 81920) {
        int tap = i % 10, q = i / 10;            // q = d*64 + cc
        dst[i] = (tap < 9) ? (short)f2b(s0[q * 9 + tap]) : (short)0;
        return;
    }
    const float* s; int off;
    if      (i < 131072) { s = s1; off = i - 81920; }
    else if (i < 147456) { s = s2; off = i - 131072; }
    else if (i < 234496) { s = s3; off = i - 147456; }
    else if (i < 278016) { s = s4; off = i - 234496; }
    else                 { s = s5; off = i - 278016; }
    dst[i] = (short)f2b(s[off]);
}

// ---------------------------------------------------------------------------
// Depthwise-weight transpose: [C][9] -> [9][C] (f32), qkv (384) + ffn (680)
// ---------------------------------------------------------------------------
__global__ __launch_bounds__(256) void twp_k(const float* __restrict__ qw,
                                             const float* __restrict__ fw,
                                             float* __restrict__ wqT,
                                             float* __restrict__ wgT) {
    int i = blockIdx.x * 256 + threadIdx.x;      // < 9576
    if (i < 3456) {
        int tap = i / 384, c = i % 384;
        wqT[i] = qw[c * 9 + tap];
    } else if (i < 9576) {
        int j = i - 3456;
        int tap = j / 680, c = j % 680;
        wgT[j] = fw[c * 9 + tap];
    }
}

// ---------------------------------------------------------------------------
// im2col 3x3 (zero pad) -> bf16 patch matrix [M][640]: col = cc*10 + tap.
// ---------------------------------------------------------------------------
__global__ __launch_bounds__(256) void unfold_k(const float* __restrict__ buf, short* __restrict__ P) {
    int idx = blockIdx.x * 256 + threadIdx.x;    // < M*64
    int cc = idx & 63;
    int t  = idx >> 6;
    int l = t & 1023, n = t >> 10;
    int y = l >> 5, x = l & 31;
    const float* src = buf + (size_t)cc * M_TOK + (n << 10);
    float v[9];
#pragma unroll
    for (int ti = 0; ti < 3; ++ti) {
        int yy = y + ti - 1;
        bool yok = (yy >= 0 && yy < 32);
#pragma unroll
        for (int tj = 0; tj < 3; ++tj) {
            int xx = x + tj - 1;
            v[ti * 3 + tj] = (yok && xx >= 0 && xx < 32) ? src[(yy << 5) + xx] : 0.f;
        }
    }
    unsigned* dst = (unsigned*)(P + (size_t)t * 640 + cc * 10);
    dst[0] = f2b(v[0]) | ((unsigned)f2b(v[1]) << 16);
    dst[1] = f2b(v[2]) | ((unsigned)f2b(v[3]) << 16);
    dst[2] = f2b(v[4]) | ((unsigned)f2b(v[5]) << 16);
    dst[3] = f2b(v[6]) | ((unsigned)f2b(v[7]) << 16);
    dst[4] = (unsigned)f2b(v[8]);
}

// ---------------------------------------------------------------------------
// bf16 MFMA GEMM (round-5 LDS version, verbatim)
// ---------------------------------------------------------------------------
template <bool ADD, bool TROUT, bool OUTBF16, bool AF32>
__global__ __launch_bounds__(256) void mm_k(const void* __restrict__ Avp,
                                            const short* __restrict__ W,
                                            void* __restrict__ outp,
                                            int M, int N, int K, int lda) {
    __shared__ __align__(16) short As[128 * 40];
    __shared__ __align__(16) short Bs[64 * 40];
    const int tid = threadIdx.x;
    const int bm = blockIdx.x * 128;
    const int bn = blockIdx.y * 64;
    const int w = tid >> 6, lane = tid & 63;
    const int h = lane >> 4, l15 = lane & 15;
    const int wm = (w >> 1) * 64, wn = (w & 1) * 32;

    f32x4 acc[4][2];
#pragma unroll
    for (int i = 0; i < 4; ++i)
#pragma unroll
        for (int j = 0; j < 2; ++j) acc[i][j] = (f32x4){0.f, 0.f, 0.f, 0.f};

    for (int k0 = 0; k0 < K; k0 += 32) {
#pragma unroll
        for (int e = 0; e < 2; ++e) {
            int li = tid + e * 256;
            int row = li >> 2, c4 = li & 3;
            int gk = k0 + c4 * 8;
            size_t abase = (size_t)(bm + row) * lda + gk;
            short tmp[8];
            if (AF32) {
                const float* ap = (const float*)Avp + abase;
                if (gk + 8 <= K) {
                    float4 va = *(const float4*)ap;
                    float4 vb = *(const float4*)(ap + 4);
                    tmp[0] = (short)f2b(va.x); tmp[1] = (short)f2b(va.y);
                    tmp[2] = (short)f2b(va.z); tmp[3] = (short)f2b(va.w);
                    tmp[4] = (short)f2b(vb.x); tmp[5] = (short)f2b(vb.y);
                    tmp[6] = (short)f2b(vb.z); tmp[7] = (short)f2b(vb.w);
                } else {
#pragma unroll
                    for (int i = 0; i < 8; ++i) tmp[i] = (gk + i < K) ? (short)f2b(ap[i]) : (short)0;
                }
            } else {
                const short* ap = (const short*)Avp + abase;
                if (gk + 8 <= K) {
                    i32x2 a = *(const i32x2*)ap;
                    i32x2 b = *(const i32x2*)(ap + 4);
                    *(i32x2*)&tmp[0] = a; *(i32x2*)&tmp[4] = b;
                } else {
#pragma unroll
                    for (int i = 0; i < 8; ++i) tmp[i] = (gk + i < K) ? ap[i] : (short)0;
                }
            }
            *(i32x4*)&As[row * 40 + c4 * 8] = *(i32x4*)tmp;
        }
        {
            int row = tid >> 2, c4 = tid & 3;
            int gk = k0 + c4 * 8;
            int gn = bn + row;
            short tmp[8];
            if (gn < N && gk + 8 <= K) {
                const short* wp = W + (size_t)gn * K + gk;
                i32x2 a = *(const i32x2*)wp;
                i32x2 b = *(const i32x2*)(wp + 4);
                *(i32x2*)&tmp[0] = a; *(i32x2*)&tmp[4] = b;
            } else {
#pragma unroll
                for (int i = 0; i < 8; ++i)
                    tmp[i] = (gn < N && gk + i < K) ? W[(size_t)gn * K + gk + i] : (short)0;
            }
            *(i32x4*)&Bs[row * 40 + c4 * 8] = *(i32x4*)tmp;
        }
        __syncthreads();
        bf16x8 af[4], bf[2];
#pragma unroll
        for (int mi = 0; mi < 4; ++mi) af[mi] = *(const bf16x8*)&As[(wm + mi * 16 + l15) * 40 + h * 8];
#pragma unroll
        for (int nj = 0; nj < 2; ++nj) bf[nj] = *(const bf16x8*)&Bs[(wn + nj * 16 + l15) * 40 + h * 8];
#pragma unroll
        for (int mi = 0; mi < 4; ++mi)
#pragma unroll
            for (int nj = 0; nj < 2; ++nj) {
                if (TROUT)
                    acc[mi][nj] = __builtin_amdgcn_mfma_f32_16x16x32_bf16(bf[nj], af[mi], acc[mi][nj], 0, 0, 0);
                else
                    acc[mi][nj] = __builtin_amdgcn_mfma_f32_16x16x32_bf16(af[mi], bf[nj], acc[mi][nj], 0, 0, 0);
            }
        __syncthreads();
    }

    if (!TROUT) {
#pragma unroll
        for (int mi = 0; mi < 4; ++mi) {
#pragma unroll
            for (int nj = 0; nj < 2; ++nj) {
                int gn = bn + wn + nj * 16 + l15;
                if (gn < N) {
#pragma unroll
                    for (int r = 0; r < 4; ++r) {
                        int gm = bm + wm + mi * 16 + h * 4 + r;
                        float v = acc[mi][nj][r];
                        size_t oi = (size_t)gm * N + gn;
                        if (OUTBF16)      ((short*)outp)[oi] = (short)f2b(v);
                        else if (ADD)     ((float*)outp)[oi] += v;
                        else              ((float*)outp)[oi] = v;
                    }
                }
            }
        }
    } else {
#pragma unroll
        for (int mi = 0; mi < 4; ++mi) {
            int gm = bm + wm + mi * 16 + l15;
#pragma unroll
            for (int nj = 0; nj < 2; ++nj)
#pragma unroll
                for (int r = 0; r < 4; ++r) {
                    int gn = bn + wn + nj * 16 + h * 4 + r;
                    if (gn < N) ((float*)outp)[(size_t)gn * M + gm] = acc[mi][nj][r];
                }
        }
    }
}

// ---------------------------------------------------------------------------
// LayerNorm D=128, fp32 in -> bf16 out.
// ---------------------------------------------------------------------------
__global__ __launch_bounds__(256) void ln_k(const float* __restrict__ in,
                                            const float* __restrict__ w,
                                            const float* __restrict__ b,
                                            short* __restrict__ out) {
    int t = blockIdx.x * 4 + (threadIdx.x >> 6);
    int lane = threadIdx.x & 63;
    float2 v = *(const float2*)(in + (size_t)t * 128 + lane * 2);
    float s = v.x + v.y, sq = v.x * v.x + v.y * v.y;
#pragma unroll
    for (int off = 32; off > 0; off >>= 1) { s += __shfl_xor(s, off); sq += __shfl_xor(sq, off); }
    float mean = s * (1.f / 128.f);
    float var = sq * (1.f / 128.f) - mean * mean;
    float rstd = rsqrtf(var + 1e-5f);
    float2 wv = *(const float2*)(w + lane * 2);
    float2 bv = *(const float2*)(b + lane * 2);
    float ox = (v.x - mean) * rstd * wv.x + bv.x;
    float oy = (v.y - mean) * rstd * wv.y + bv.y;
    ((unsigned*)out)[(size_t)t * 64 + lane] = f2b(ox) | ((unsigned)f2b(oy) << 16);
}

// ---------------------------------------------------------------------------
// Fused qkv depthwise 3x3 + l2norm(q,k heads).
// ---------------------------------------------------------------------------
__global__ __launch_bounds__(256) void dwl2n_k(const short* __restrict__ in,
                                               const float* __restrict__ wqT,
                                               short* __restrict__ out) {
    int idx = blockIdx.x * 256 + threadIdx.x;    // < M*48
    int q = idx % 48;
    int t = idx / 48;
    int c0 = q * 8;
    int l = t & 1023, n = t >> 10;
    int y = l >> 5, x = l & 31;
    int tb = n << 10;

    float acc[8];
#pragma unroll
    for (int k = 0; k < 8; ++k) acc[k] = 0.f;

#pragma unroll
    for (int i = 0; i < 3; ++i) {
        int yy = y + i - 1;
        if (yy < 0 || yy >= 32) continue;
#pragma unroll
        for (int j = 0; j < 3; ++j) {
            int xx = x + j - 1;
            if (xx < 0 || xx >= 32) continue;
            bf16x8 d = *(const bf16x8*)(in + (size_t)(tb + (yy << 5) + xx) * 384 + c0);
            float4 wa = *(const float4*)(wqT + (i * 3 + j) * 384 + c0);
            float4 wb = *(const float4*)(wqT + (i * 3 + j) * 384 + c0 + 4);
            acc[0] += b2f((unsigned short)d[0]) * wa.x;
            acc[1] += b2f((unsigned short)d[1]) * wa.y;
            acc[2] += b2f((unsigned short)d[2]) * wa.z;
            acc[3] += b2f((unsigned short)d[3]) * wa.w;
            acc[4] += b2f((unsigned short)d[4]) * wb.x;
            acc[5] += b2f((unsigned short)d[5]) * wb.y;
            acc[6] += b2f((unsigned short)d[6]) * wb.z;
            acc[7] += b2f((unsigned short)d[7]) * wb.w;
        }
    }
    float ss = 0.f;
#pragma unroll
    for (int k = 0; k < 8; ++k) ss += acc[k] * acc[k];
    ss += __shfl_xor(ss, 1);
    ss += __shfl_xor(ss, 2);
    float sc = (c0 < 256) ? (1.f / fmaxf(sqrtf(ss), 1e-12f)) : 1.f;
    unsigned o[4];
#pragma unroll
    for (int k = 0; k < 4; ++k)
        o[k] = f2b(acc[2 * k] * sc) | ((unsigned)f2b(acc[2 * k + 1] * sc) << 16);
    *(i32x4*)(out + (size_t)t * 384 + c0) = *(i32x4*)o;
}

// ---------------------------------------------------------------------------
// Fused GDFN depthwise (round-5 version, out lda = 344).
// ---------------------------------------------------------------------------
__global__ __launch_bounds__(256) void gdfn2_k(const short* __restrict__ in,
                                               const float* __restrict__ wgT,
                                               short* __restrict__ out) {
    int idx = blockIdx.x * 256 + threadIdx.x;    // < M*43
    int q = idx % 43;
    int t = idx / 43;
    int c0 = q * 8;
    int l = t & 1023, n = t >> 10;
    int y = l >> 5, x = l & 31;
    int tb = n << 10;

    float a[8], g[8];
#pragma unroll
    for (int k = 0; k < 8; ++k) { a[k] = 0.f; g[k] = 0.f; }

#pragma unroll
    for (int i = 0; i < 3; ++i) {
        int yy = y + i - 1;
        if (yy < 0 || yy >= 32) continue;
#pragma unroll
        for (int j = 0; j < 3; ++j) {
            int xx = x + j - 1;
            if (xx < 0 || xx >= 32) continue;
            const short* p = in + (size_t)(tb + (yy << 5) + xx) * 680 + c0;
            bf16x8 d1 = *(const bf16x8*)p;
            i32x2 d2a = *(const i32x2*)(p + 340);
            i32x2 d2b = *(const i32x2*)(p + 344);
            short d2[8];
            *(i32x2*)&d2[0] = d2a; *(i32x2*)&d2[4] = d2b;
            const float* wp = wgT + (i * 3 + j) * 680 + c0;
            float4 w1a = *(const float4*)wp;
            float4 w1b = *(const float4*)(wp + 4);
            float w1[8] = {w1a.x, w1a.y, w1a.z, w1a.w, w1b.x, w1b.y, w1b.z, w1b.w};
            float w2[8];
#pragma unroll
            for (int k = 0; k < 8; ++k) w2[k] = wp[340 + k];
#pragma unroll
            for (int k = 0; k < 8; ++k) {
                a[k] += b2f((unsigned short)d1[k]) * w1[k];
                g[k] += b2f((unsigned short)d2[k]) * w2[k];
            }
        }
    }
    unsigned o[4];
#pragma unroll
    for (int k = 0; k < 4; ++k) {
        float r0 = 0.5f * a[2 * k] * (1.f + erff(a[2 * k] * 0.70710678118f)) * g[2 * k];
        float r1 = 0.5f * a[2 * k + 1] * (1.f + erff(a[2 * k + 1] * 0.70710678118f)) * g[2 * k + 1];
        o[k] = f2b(r0) | ((unsigned)f2b(r1) << 16);
    }
    short* op = out + (size_t)t * 344 + c0;
    if (q < 42) *(i32x4*)op = *(i32x4*)o;
    else        *(i32x2*)op = (i32x2){(int)o[0], (int)o[1]};
}

// ---------------------------------------------------------------------------
// V transpose: qkvb V-section [t][c] -> VT[(n*4+hd)*32 + c][1024 keys]
// ---------------------------------------------------------------------------
__global__ __launch_bounds__(256) void vt_k(const short* __restrict__ qkv, short* __restrict__ VT) {
    __shared__ __align__(16) short L[64 * 40];
    const int bid = blockIdx.x;                  // 1600 = nh*16 + kb
    const int kb = bid & 15, nh = bid >> 4;
    const int hd = nh & 3, n = nh >> 2;
    const int tid = threadIdx.x;
    {
        int key = tid >> 2, c0 = (tid & 3) * 8;
        const short* p = qkv + ((size_t)(n << 10) + kb * 64 + key) * 384 + 256 + hd * 32 + c0;
        *(i32x4*)&L[key * 40 + c0] = *(const i32x4*)p;
    }
    __syncthreads();
    {
        int c = tid >> 3, k8 = (tid & 7) * 8;
        short v[8];
#pragma unroll
        for (int i = 0; i < 8; ++i) v[i] = L[(k8 + i) * 40 + c];
        *(i32x4*)(VT + ((size_t)nh * 32 + c) * 1024 + kb * 64 + k8) = *(i32x4*)v;
    }
}

// ---------------------------------------------------------------------------
// MFMA flash attention — BISECT: round-5 structure (LDS K double-buffer,
// one barrier/tile, register prefetch, fixed-bound softmax) with ONLY the
// V source changed: V-fragments read from VT (round-7 addressing).
// ---------------------------------------------------------------------------
__global__ __launch_bounds__(256) void attn_k(const short* __restrict__ qkv,
                                              const short* __restrict__ VT,
                                              const float* __restrict__ temp,
                                              short* __restrict__ outp) {
    __shared__ __align__(16) short Ks[2][64 * 40];
    const int bid = blockIdx.x;              // 800 = nh*8 + qt
    const int qt = bid & 7, nh = bid >> 3;
    const int hd = nh & 3, n = nh >> 2;
    const int tid = threadIdx.x;
    const int w = tid >> 6, lane = tid & 63;
    const int h = lane >> 4, l15 = lane & 15;
    const size_t base = (size_t)n * 1024 * 384;
    const int qrowA = qt * 128 + w * 16 + l15;
    const float ts2 = temp[hd] * 1.44269504089f;
    const float nbound = -(fabsf(ts2) + 0.25f);

    bf16x8 qfA = *(const bf16x8*)(qkv + base + (size_t)qrowA * 384 + hd * 32 + h * 8);
    bf16x8 qfB = *(const bf16x8*)(qkv + base + (size_t)(qrowA + 64) * 384 + hd * 32 + h * 8);
    f32x4 oA0 = {0.f,0.f,0.f,0.f}, oA1 = {0.f,0.f,0.f,0.f};
    f32x4 oB0 = {0.f,0.f,0.f,0.f}, oB1 = {0.f,0.f,0.f,0.f};
    float psA = 0.f, psB = 0.f;

    // K staging (round-5): thread -> (key, c4)
    const int skey = tid >> 2, sc4 = tid & 3;
    const short* kbase = qkv + base + (size_t)skey * 384 + 128 + hd * 32 + sc4 * 8;
    i32x4 kreg = *(const i32x4*)kbase;

    // V source (round-7): pre-transposed VT, channel = l15 (+16), key = 4h-based slots
    const short* V0 = VT + ((size_t)nh * 32 + l15) * 1024 + 4 * h;
    const short* V1 = V0 + 16 * 1024;

    for (int t = 0; t < 16; ++t) {
        const int nb = t & 1;
        *(i32x4*)&Ks[nb][skey * 40 + sc4 * 8] = kreg;
        if (t < 15) kreg = *(const i32x4*)(kbase + (size_t)(t + 1) * 64 * 384);
        __syncthreads();
        const int j0 = t * 64;

        const bf16x8 kf0 = *(const bf16x8*)&Ks[nb][l15 * 40 + h * 8];
        const bf16x8 kf1 = *(const bf16x8*)&Ks[nb][(16 + l15) * 40 + h * 8];
        const bf16x8 kf2 = *(const bf16x8*)&Ks[nb][(32 + l15) * 40 + h * 8];
        const bf16x8 kf3 = *(const bf16x8*)&Ks[nb][(48 + l15) * 40 + h * 8];

        union { int u[4]; bf16x8 v; } va0, va1, vb0, vb1;
        *(i32x2*)&va0.u[0] = *(const i32x2*)(V0 + j0);
        *(i32x2*)&va0.u[2] = *(const i32x2*)(V0 + j0 + 16);
        *(i32x2*)&va1.u[0] = *(const i32x2*)(V1 + j0);
        *(i32x2*)&va1.u[2] = *(const i32x2*)(V1 + j0 + 16);
        *(i32x2*)&vb0.u[0] = *(const i32x2*)(V0 + j0 + 32);
        *(i32x2*)&vb0.u[2] = *(const i32x2*)(V0 + j0 + 48);
        *(i32x2*)&vb1.u[0] = *(const i32x2*)(V1 + j0 + 32);
        *(i32x2*)&vb1.u[2] = *(const i32x2*)(V1 + j0 + 48);
        const f32x4 z = {0.f, 0.f, 0.f, 0.f};

        // ---- q-set A ----
        {
            f32x4 s0 = __builtin_amdgcn_mfma_f32_16x16x32_bf16(kf0, qfA, z, 0, 0, 0);
            f32x4 s1 = __builtin_amdgcn_mfma_f32_16x16x32_bf16(kf1, qfA, z, 0, 0, 0);
            f32x4 s2 = __builtin_amdgcn_mfma_f32_16x16x32_bf16(kf2, qfA, z, 0, 0, 0);
            f32x4 s3 = __builtin_amdgcn_mfma_f32_16x16x32_bf16(kf3, qfA, z, 0, 0, 0);
            float p[16];
#pragma unroll
            for (int r = 0; r < 4; ++r) {
                p[r]      = exp2f(fmaf(s0[r], ts2, nbound));
                p[4 + r]  = exp2f(fmaf(s1[r], ts2, nbound));
                p[8 + r]  = exp2f(fmaf(s2[r], ts2, nbound));
                p[12 + r] = exp2f(fmaf(s3[r], ts2, nbound));
            }
#pragma unroll
            for (int r = 0; r < 16; ++r) psA += p[r];
            union { unsigned u[4]; bf16x8 v; } pf1, pf2;
#pragma unroll
            for (int r = 0; r < 4; ++r) {
                pf1.u[r] = cvtpk(p[2 * r], p[2 * r + 1]);
                pf2.u[r] = cvtpk(p[8 + 2 * r], p[8 + 2 * r + 1]);
            }
            oA0 = __builtin_amdgcn_mfma_f32_16x16x32_bf16(va0.v, pf1.v, oA0, 0, 0, 0);
            oA1 = __builtin_amdgcn_mfma_f32_16x16x32_bf16(va1.v, pf1.v, oA1, 0, 0, 0);
            oA0 = __builtin_amdgcn_mfma_f32_16x16x32_bf16(vb0.v, pf2.v, oA0, 0, 0, 0);
            oA1 = __builtin_amdgcn_mfma_f32_16x16x32_bf16(vb1.v, pf2.v, oA1, 0, 0, 0);
        }
        // ---- q-set B ----
        {
            f32x4 s0 = __builtin_amdgcn_mfma_f32_16x16x32_bf16(kf0, qfB, z, 0, 0, 0);
            f32x4 s1 = __builtin_amdgcn_mfma_f32_16x16x32_bf16(kf1, qfB, z, 0, 0, 0);
            f32x4 s2 = __builtin_amdgcn_mfma_f32_16x16x32_bf16(kf2, qfB, z, 0, 0, 0);
            f32x4 s3 = __builtin_amdgcn_mfma_f32_16x16x32_bf16(kf3, qfB, z, 0, 0, 0);
            float p[16];
#pragma unroll
            for (int r = 0; r < 4; ++r) {
                p[r]      = exp2f(fmaf(s0[r], ts2, nbound));
                p[4 + r]  = exp2f(fmaf(s1[r], ts2, nbound));
                p[8 + r]  = exp2f(fmaf(s2[r], ts2, nbound));
                p[12 + r] = exp2f(fmaf(s3[r], ts2, nbound));
            }
#pragma unroll
            for (int r = 0; r < 16; ++r) psB += p[r];
            union { unsigned u[4]; bf16x8 v; } pf1, pf2;
#pragma unroll
            for (int r = 0; r < 4; ++r) {
                pf1.u[r] = cvtpk(p[2 * r], p[2 * r + 1]);
                pf2.u[r] = cvtpk(p[8 + 2 * r], p[8 + 2 * r + 1]);
            }
            oB0 = __builtin_amdgcn_mfma_f32_16x16x32_bf16(va0.v, pf1.v, oB0, 0, 0, 0);
            oB1 = __builtin_amdgcn_mfma_f32_16x16x32_bf16(va1.v, pf1.v, oB1, 0, 0, 0);
            oB0 = __builtin_amdgcn_mfma_f32_16x16x32_bf16(vb0.v, pf2.v, oB0, 0, 0, 0);
            oB1 = __builtin_amdgcn_mfma_f32_16x16x32_bf16(vb1.v, pf2.v, oB1, 0, 0, 0);
        }
    }

    psA += __shfl_xor(psA, 16); psA += __shfl_xor(psA, 32);
    psB += __shfl_xor(psB, 16); psB += __shfl_xor(psB, 32);
    float invA = 1.f / psA, invB = 1.f / psB;

    size_t obA = ((size_t)n * 1024 + qrowA) * 128 + hd * 32;
    size_t obB = obA + (size_t)64 * 128;
    unsigned u;
    u = f2b(oA0[0] * invA) | ((unsigned)f2b(oA0[1] * invA) << 16); *(unsigned*)(outp + obA + h * 4) = u;
    u = f2b(oA0[2] * invA) | ((unsigned)f2b(oA0[3] * invA) << 16); *(unsigned*)(outp + obA + h * 4 + 2) = u;
    u = f2b(oA1[0] * invA) | ((unsigned)f2b(oA1[1] * invA) << 16); *(unsigned*)(outp + obA + 16 + h * 4) = u;
    u = f2b(oA1[2] * invA) | ((unsigned)f2b(oA1[3] * invA) << 16); *(unsigned*)(outp + obA + 16 + h * 4 + 2) = u;
    u = f2b(oB0[0] * invB) | ((unsigned)f2b(oB0[1] * invB) << 16); *(unsigned*)(outp + obB + h * 4) = u;
    u = f2b(oB0[2] * invB) | ((unsigned)f2b(oB0[3] * invB) << 16); *(unsigned*)(outp + obB + h * 4 + 2) = u;
    u = f2b(oB1[0] * invB) | ((unsigned)f2b(oB1[1] * invB) << 16); *(unsigned*)(outp + obB + 16 + h * 4) = u;
    u = f2b(oB1[2] * invB) | ((unsigned)f2b(oB1[3] * invB) << 16); *(unsigned*)(outp + obB + 16 + h * 4 + 2) = u;
}

// ---------------------------------------------------------------------------
extern "C" void kernel_launch(void* const* d_in, const int* in_sizes, int n_in,
                              void* d_out, int out_size, void* d_ws, size_t ws_size,
                              hipStream_t stream) {
    const float* buffer      = (const float*)d_in[0];
    const float* mlp_w       = (const float*)d_in[1];
    const float* ln_attn_w   = (const float*)d_in[2];
    const float* ln_attn_b   = (const float*)d_in[3];
    const float* ln_ffn_w    = (const float*)d_in[4];
    const float* ln_ffn_b    = (const float*)d_in[5];
    const float* qkv_w       = (const float*)d_in[6];
    const float* qkv_dw_w    = (const float*)d_in[7];
    const float* temperature = (const float*)d_in[8];
    const float* proj_attn_w = (const float*)d_in[9];
    const float* ffn_in_w    = (const float*)d_in[10];
    const float* ffn_dw_w    = (const float*)d_in[11];
    const float* ffn_out_w   = (const float*)d_in[12];
    const float* proj3d_w    = (const float*)d_in[13];

    char* wsb = (char*)d_ws;
    short* Wbf     = (short*)wsb;                 // 286208 bf16 weights (round-5 layout)
    short* mlpW    = Wbf;                         // [128][640]
    short* qkvW    = Wbf + 81920;                 // [384][128]
    short* projW   = Wbf + 131072;                // [128][128]
    short* ffnInW  = Wbf + 147456;                // [680][128]
    short* ffnOutW = Wbf + 234496;                // [128][340]
    short* p3dW    = Wbf + 278016;                // [64][128]
    float* wqT     = (float*)(wsb + 573440);      // [9][384] f32
    float* wgT     = (float*)(wsb + 587264);      // [9][680] f32
    short* PatchB  = (short*)(wsb + 611840);      // [M][640] bf16
    float* tok     = (float*)(wsb + 33379840);    // [M][128] f32
    short* LNbf    = (short*)(wsb + 46487040);    // [M][128] bf16
    short* QKVpre  = (short*)(wsb + 53040640);    // [M][384] bf16
    short* qkvb    = (short*)(wsb + 72701440);    // [M][384] bf16
    short* AObf    = (short*)(wsb + 92362240);    // [M][128] bf16
    short* F1      = (short*)(wsb + 98915840);    // [M][680] bf16
    short* G       = (short*)(wsb + 133731840);   // [M][344] bf16 (lda 344)
    short* VT      = (short*)(wsb + 151344640);   // [100][32][1024] bf16

    dim3 blk(256);

    cvtw_k<<<1118, blk, 0, stream>>>(mlp_w, qkv_w, proj_attn_w, ffn_in_w, ffn_out_w, proj3d_w, Wbf);
    twp_k<<<38, blk, 0, stream>>>(qkv_dw_w, ffn_dw_w, wqT, wgT);
    unfold_k<<<6400, blk, 0, stream>>>(buffer, PatchB);

    // S2T: tok = patches @ mlp_w^T (f32 out), K padded to 640
    mm_k<false, false, false, false><<<dim3(200, 2), blk, 0, stream>>>(PatchB, mlpW, tok, M_TOK, 128, 640, 640);
    ln_k<<<6400, blk, 0, stream>>>(tok, ln_attn_w, ln_attn_b, LNbf);
    // qkv 1x1 (bf16 out)
    mm_k<false, false, true, false><<<dim3(200, 6), blk, 0, stream>>>(LNbf, qkvW, QKVpre, M_TOK, 384, 128, 128);
    // fused dwconv + l2norm
    dwl2n_k<<<4800, blk, 0, stream>>>(QKVpre, wqT, qkvb);
    // V transpose + bisect attention (LDS K, VT-sourced V)
    vt_k<<<1600, blk, 0, stream>>>(qkvb, VT);
    attn_k<<<800, blk, 0, stream>>>(qkvb, VT, temperature, AObf);
    // proj + residual
    mm_k<true, false, false, false><<<dim3(200, 2), blk, 0, stream>>>(AObf, projW, tok, M_TOK, 128, 128, 128);
    ln_k<<<6400, blk, 0, stream>>>(tok, ln_ffn_w, ln_ffn_b, LNbf);
    // ffn_in 1x1 (bf16 out)
    mm_k<false, false, true, false><<<dim3(200, 11), blk, 0, stream>>>(LNbf, ffnInW, F1, M_TOK, 680, 128, 128);
    // fused GDFN dwconv + gelu gate
    gdfn2_k<<<4300, blk, 0, stream>>>(F1, wgT, G);
    // ffn_out + residual (A lda = 344)
    mm_k<true, false, false, false><<<dim3(200, 2), blk, 0, stream>>>(G, ffnOutW, tok, M_TOK, 128, 340, 344);
    // Token2SAI (transposed product, coalesced)
    mm_k<false, true, false, true><<<dim3(200, 1), blk, 0, stream>>>(tok, p3dW, d_out, M_TOK, 64, 128, 128);
}

// Round 9
// 274.622 us; speedup vs baseline: 1.0191x; 1.0191x over previous
//
#include <hip/hip_runtime.h>
#include <math.h>

#define M_TOK 25600   // 25 images * 1024 tokens

typedef __attribute__((ext_vector_type(8))) short bf16x8;
typedef __attribute__((ext_vector_type(4))) float f32x4;
typedef __attribute__((ext_vector_type(4))) int   i32x4;
typedef __attribute__((ext_vector_type(2))) int   i32x2;

__device__ __forceinline__ unsigned short f2b(float x) {
    unsigned u = __builtin_bit_cast(unsigned, x);
    return (unsigned short)((u + 0x7fffu + ((u >> 16) & 1u)) >> 16);
}
__device__ __forceinline__ float b2f(unsigned short h) {
    unsigned u = ((unsigned)h) << 16;
    return __builtin_bit_cast(float, u);
}
__device__ __forceinline__ unsigned cvtpk(float lo, float hi) {
    unsigned r;
    asm("v_cvt_pk_bf16_f32 %0, %1, %2" : "=v"(r) : "v"(lo), "v"(hi));
    return r;
}

// ---------------------------------------------------------------------------
// Weight fp32->bf16. mlp_w -> [128][64][10] (tap 9 zero, K=640);
// ffn_out_w -> [128][352] (cols 340..351 zero, K=352). Others packed.
// ---------------------------------------------------------------------------
__global__ __launch_bounds__(256) void cvtw_k(const float* __restrict__ s0, const float* __restrict__ s1,
                                              const float* __restrict__ s2, const float* __restrict__ s3,
                                              const float* __restrict__ s4, const float* __restrict__ s5,
                                              short* __restrict__ dst) {
    int i = blockIdx.x * 256 + threadIdx.x;      // < 287744
    if (i >= 287744) return;
    if (i < 81920) {
        int tap = i % 10, q = i / 10;
        dst[i] = (tap < 9) ? (short)f2b(s0[q * 9 + tap]) : (short)0;
        return;
    }
    if (i >= 234496 && i < 279552) {             // ffn_out padded [128][352]
        int l = i - 234496;
        int row = l / 352, col = l % 352;
        dst[i] = (col < 340) ? (short)f2b(s4[row * 340 + col]) : (short)0;
        return;
    }
    const float* s; int off;
    if      (i < 131072) { s = s1; off = i - 81920; }
    else if (i < 147456) { s = s2; off = i - 131072; }
    else if (i < 234496) { s = s3; off = i - 147456; }
    else                 { s = s5; off = i - 279552; }
    dst[i] = (short)f2b(s[off]);
}

// ---------------------------------------------------------------------------
// Depthwise-weight transpose: [C][9] -> [9][C] (f32), qkv (384) + ffn (680)
// ---------------------------------------------------------------------------
__global__ __launch_bounds__(256) void twp_k(const float* __restrict__ qw,
                                             const float* __restrict__ fw,
                                             float* __restrict__ wqT,
                                             float* __restrict__ wgT) {
    int i = blockIdx.x * 256 + threadIdx.x;      // < 9576
    if (i < 3456) {
        int tap = i / 384, c = i % 384;
        wqT[i] = qw[c * 9 + tap];
    } else if (i < 9576) {
        int j = i - 3456;
        int tap = j / 680, c = j % 680;
        wgT[j] = fw[c * 9 + tap];
    }
}

// ---------------------------------------------------------------------------
// im2col 3x3 (zero pad) -> bf16 patch matrix [M][640]: col = cc*10 + tap.
// ---------------------------------------------------------------------------
__global__ __launch_bounds__(256) void unfold_k(const float* __restrict__ buf, short* __restrict__ P) {
    int idx = blockIdx.x * 256 + threadIdx.x;    // < M*64
    int cc = idx & 63;
    int t  = idx >> 6;
    int l = t & 1023, n = t >> 10;
    int y = l >> 5, x = l & 31;
    const float* src = buf + (size_t)cc * M_TOK + (n << 10);
    float v[9];
#pragma unroll
    for (int ti = 0; ti < 3; ++ti) {
        int yy = y + ti - 1;
        bool yok = (yy >= 0 && yy < 32);
#pragma unroll
        for (int tj = 0; tj < 3; ++tj) {
            int xx = x + tj - 1;
            v[ti * 3 + tj] = (yok && xx >= 0 && xx < 32) ? src[(yy << 5) + xx] : 0.f;
        }
    }
    unsigned* dst = (unsigned*)(P + (size_t)t * 640 + cc * 10);
    dst[0] = f2b(v[0]) | ((unsigned)f2b(v[1]) << 16);
    dst[1] = f2b(v[2]) | ((unsigned)f2b(v[3]) << 16);
    dst[2] = f2b(v[4]) | ((unsigned)f2b(v[5]) << 16);
    dst[3] = f2b(v[6]) | ((unsigned)f2b(v[7]) << 16);
    dst[4] = (unsigned)f2b(v[8]);
}

// ---------------------------------------------------------------------------
// BISECT TARGET: bf16 MFMA GEMM v2 — zero LDS, zero barriers.
// out[M x N] (+=) A[M x K] * W[N x K]^T. 128x64 tile, 4 waves (2x2).
// Fragments loaded directly from global (16B/lane, coalesced across l15).
// ---------------------------------------------------------------------------
template <bool ADD, bool TROUT, bool OUTBF16, bool AF32, int N, int K>
__global__ __launch_bounds__(256) void mm_k(const void* __restrict__ Avp,
                                            const short* __restrict__ W,
                                            void* __restrict__ outp) {
    const int tid = threadIdx.x;
    const int bm = blockIdx.x * 128;
    const int bn = blockIdx.y * 64;
    const int w = tid >> 6, lane = tid & 63;
    const int h = lane >> 4, l15 = lane & 15;
    const int wm = (w >> 1) * 64, wn = (w & 1) * 32;

    f32x4 acc[4][2];
#pragma unroll
    for (int i = 0; i < 4; ++i)
#pragma unroll
        for (int j = 0; j < 2; ++j) acc[i][j] = (f32x4){0.f, 0.f, 0.f, 0.f};

    const short* arow[4];
    const float* arowf[4];
#pragma unroll
    for (int mi = 0; mi < 4; ++mi) {
        size_t r = (size_t)(bm + wm + mi * 16 + l15) * K;
        if (AF32) arowf[mi] = (const float*)Avp + r;
        else      arow[mi]  = (const short*)Avp + r;
    }
    const short* wrow[2];
    bool wok[2];
#pragma unroll
    for (int nj = 0; nj < 2; ++nj) {
        int gn = bn + wn + nj * 16 + l15;
        wok[nj] = (N % 64 == 0) || (gn < N);
        wrow[nj] = W + (size_t)(wok[nj] ? gn : 0) * K;
    }
    const bf16x8 zf = {0, 0, 0, 0, 0, 0, 0, 0};

    for (int k0 = 0; k0 < K; k0 += 32) {
        const int gk = k0 + h * 8;
        bf16x8 af[4], bf[2];
#pragma unroll
        for (int mi = 0; mi < 4; ++mi) {
            if (AF32) {
                float4 va = *(const float4*)(arowf[mi] + gk);
                float4 vb = *(const float4*)(arowf[mi] + gk + 4);
                union { unsigned u[4]; bf16x8 v; } t;
                t.u[0] = cvtpk(va.x, va.y); t.u[1] = cvtpk(va.z, va.w);
                t.u[2] = cvtpk(vb.x, vb.y); t.u[3] = cvtpk(vb.z, vb.w);
                af[mi] = t.v;
            } else {
                af[mi] = *(const bf16x8*)(arow[mi] + gk);
            }
        }
#pragma unroll
        for (int nj = 0; nj < 2; ++nj)
            bf[nj] = wok[nj] ? *(const bf16x8*)(wrow[nj] + gk) : zf;
#pragma unroll
        for (int mi = 0; mi < 4; ++mi)
#pragma unroll
            for (int nj = 0; nj < 2; ++nj) {
                if (TROUT)
                    acc[mi][nj] = __builtin_amdgcn_mfma_f32_16x16x32_bf16(bf[nj], af[mi], acc[mi][nj], 0, 0, 0);
                else
                    acc[mi][nj] = __builtin_amdgcn_mfma_f32_16x16x32_bf16(af[mi], bf[nj], acc[mi][nj], 0, 0, 0);
            }
    }

    if (!TROUT) {
#pragma unroll
        for (int mi = 0; mi < 4; ++mi) {
#pragma unroll
            for (int nj = 0; nj < 2; ++nj) {
                int gn = bn + wn + nj * 16 + l15;
                if (gn < N) {
#pragma unroll
                    for (int r = 0; r < 4; ++r) {
                        int gm = bm + wm + mi * 16 + h * 4 + r;
                        float v = acc[mi][nj][r];
                        size_t oi = (size_t)gm * N + gn;
                        if (OUTBF16)      ((short*)outp)[oi] = (short)f2b(v);
                        else if (ADD)     ((float*)outp)[oi] += v;
                        else              ((float*)outp)[oi] = v;
                    }
                }
            }
        }
    } else {
#pragma unroll
        for (int mi = 0; mi < 4; ++mi) {
            int gm = bm + wm + mi * 16 + l15;
#pragma unroll
            for (int nj = 0; nj < 2; ++nj)
#pragma unroll
                for (int r = 0; r < 4; ++r) {
                    int gn = bn + wn + nj * 16 + h * 4 + r;
                    if (gn < N) ((float*)outp)[(size_t)gn * M_TOK + gm] = acc[mi][nj][r];
                }
        }
    }
}

// ---------------------------------------------------------------------------
// LayerNorm D=128, fp32 in -> bf16 out.
// ---------------------------------------------------------------------------
__global__ __launch_bounds__(256) void ln_k(const float* __restrict__ in,
                                            const float* __restrict__ w,
                                            const float* __restrict__ b,
                                            short* __restrict__ out) {
    int t = blockIdx.x * 4 + (threadIdx.x >> 6);
    int lane = threadIdx.x & 63;
    float2 v = *(const float2*)(in + (size_t)t * 128 + lane * 2);
    float s = v.x + v.y, sq = v.x * v.x + v.y * v.y;
#pragma unroll
    for (int off = 32; off > 0; off >>= 1) { s += __shfl_xor(s, off); sq += __shfl_xor(sq, off); }
    float mean = s * (1.f / 128.f);
    float var = sq * (1.f / 128.f) - mean * mean;
    float rstd = rsqrtf(var + 1e-5f);
    float2 wv = *(const float2*)(w + lane * 2);
    float2 bv = *(const float2*)(b + lane * 2);
    float ox = (v.x - mean) * rstd * wv.x + bv.x;
    float oy = (v.y - mean) * rstd * wv.y + bv.y;
    ((unsigned*)out)[(size_t)t * 64 + lane] = f2b(ox) | ((unsigned)f2b(oy) << 16);
}

// ---------------------------------------------------------------------------
// Fused qkv depthwise 3x3 + l2norm(q,k heads).
// ---------------------------------------------------------------------------
__global__ __launch_bounds__(256) void dwl2n_k(const short* __restrict__ in,
                                               const float* __restrict__ wqT,
                                               short* __restrict__ out) {
    int idx = blockIdx.x * 256 + threadIdx.x;    // < M*48
    int q = idx % 48;
    int t = idx / 48;
    int c0 = q * 8;
    int l = t & 1023, n = t >> 10;
    int y = l >> 5, x = l & 31;
    int tb = n << 10;

    float acc[8];
#pragma unroll
    for (int k = 0; k < 8; ++k) acc[k] = 0.f;

#pragma unroll
    for (int i = 0; i < 3; ++i) {
        int yy = y + i - 1;
        if (yy < 0 || yy >= 32) continue;
#pragma unroll
        for (int j = 0; j < 3; ++j) {
            int xx = x + j - 1;
            if (xx < 0 || xx >= 32) continue;
            bf16x8 d = *(const bf16x8*)(in + (size_t)(tb + (yy << 5) + xx) * 384 + c0);
            float4 wa = *(const float4*)(wqT + (i * 3 + j) * 384 + c0);
            float4 wb = *(const float4*)(wqT + (i * 3 + j) * 384 + c0 + 4);
            acc[0] += b2f((unsigned short)d[0]) * wa.x;
            acc[1] += b2f((unsigned short)d[1]) * wa.y;
            acc[2] += b2f((unsigned short)d[2]) * wa.z;
            acc[3] += b2f((unsigned short)d[3]) * wa.w;
            acc[4] += b2f((unsigned short)d[4]) * wb.x;
            acc[5] += b2f((unsigned short)d[5]) * wb.y;
            acc[6] += b2f((unsigned short)d[6]) * wb.z;
            acc[7] += b2f((unsigned short)d[7]) * wb.w;
        }
    }
    float ss = 0.f;
#pragma unroll
    for (int k = 0; k < 8; ++k) ss += acc[k] * acc[k];
    ss += __shfl_xor(ss, 1);
    ss += __shfl_xor(ss, 2);
    float sc = (c0 < 256) ? (1.f / fmaxf(sqrtf(ss), 1e-12f)) : 1.f;
    unsigned o[4];
#pragma unroll
    for (int k = 0; k < 4; ++k)
        o[k] = f2b(acc[2 * k] * sc) | ((unsigned)f2b(acc[2 * k + 1] * sc) << 16);
    *(i32x4*)(out + (size_t)t * 384 + c0) = *(i32x4*)o;
}

// ---------------------------------------------------------------------------
// Fused GDFN depthwise: dual 3x3 dwconv + exact gelu gate. out [M][352],
// cols 340..351 zeroed (zero-padded K for the following GEMM).
// ---------------------------------------------------------------------------
__global__ __launch_bounds__(256) void gdfn2_k(const short* __restrict__ in,
                                               const float* __restrict__ wgT,
                                               short* __restrict__ out) {
    int idx = blockIdx.x * 256 + threadIdx.x;    // < M*44
    int q = idx % 44;
    int t = idx / 44;
    int c0 = q * 8;
    short* op = out + (size_t)t * 352 + c0;
    if (q == 43) {                               // pure pad chunk 344..351
        *(i32x4*)op = (i32x4){0, 0, 0, 0};
        return;
    }
    int l = t & 1023, n = t >> 10;
    int y = l >> 5, x = l & 31;
    int tb = n << 10;

    float a[8], g[8];
#pragma unroll
    for (int k = 0; k < 8; ++k) { a[k] = 0.f; g[k] = 0.f; }

#pragma unroll
    for (int i = 0; i < 3; ++i) {
        int yy = y + i - 1;
        if (yy < 0 || yy >= 32) continue;
#pragma unroll
        for (int j = 0; j < 3; ++j) {
            int xx = x + j - 1;
            if (xx < 0 || xx >= 32) continue;
            const short* p = in + (size_t)(tb + (yy << 5) + xx) * 680 + c0;
            bf16x8 d1 = *(const bf16x8*)p;
            i32x2 d2a = *(const i32x2*)(p + 340);
            i32x2 d2b = *(const i32x2*)(p + 344);
            short d2[8];
            *(i32x2*)&d2[0] = d2a; *(i32x2*)&d2[4] = d2b;
            const float* wp = wgT + (i * 3 + j) * 680 + c0;
            float4 w1a = *(const float4*)wp;
            float4 w1b = *(const float4*)(wp + 4);
            float w1[8] = {w1a.x, w1a.y, w1a.z, w1a.w, w1b.x, w1b.y, w1b.z, w1b.w};
            float w2[8];
#pragma unroll
            for (int k = 0; k < 8; ++k) w2[k] = wp[340 + k];
#pragma unroll
            for (int k = 0; k < 8; ++k) {
                a[k] += b2f((unsigned short)d1[k]) * w1[k];
                g[k] += b2f((unsigned short)d2[k]) * w2[k];
            }
        }
    }
    unsigned o[4];
#pragma unroll
    for (int k = 0; k < 4; ++k) {
        float r0 = 0.5f * a[2 * k] * (1.f + erff(a[2 * k] * 0.70710678118f)) * g[2 * k];
        float r1 = 0.5f * a[2 * k + 1] * (1.f + erff(a[2 * k + 1] * 0.70710678118f)) * g[2 * k + 1];
        o[k] = f2b(r0) | ((unsigned)f2b(r1) << 16);
    }
    if (q == 42) { o[2] = 0; o[3] = 0; }         // cols 340..343 are pad
    *(i32x4*)op = *(i32x4*)o;
}

// ---------------------------------------------------------------------------
// MFMA flash attention (round-5 version, verbatim — PROVEN at 53.7us):
// 128 q-rows/block, K-tile 64, zero-shuffle PV via pre-permuted Vp LDS,
// fixed-bound softmax, double-buffered LDS, one barrier/tile, reg prefetch.
// ---------------------------------------------------------------------------
__global__ __launch_bounds__(256) void attn_k(const short* __restrict__ qkv,
                                              const float* __restrict__ temp,
                                              short* __restrict__ outp) {
    __shared__ __align__(16) short Ks[2][64 * 40];
    __shared__ __align__(16) short Vp[2][2048];
    const int bid = blockIdx.x;              // 800 = 25n * 4hd * 8qt
    const int qt = bid & 7, nh = bid >> 3;
    const int hd = nh & 3, n = nh >> 2;
    const int tid = threadIdx.x;
    const int w = tid >> 6, lane = tid & 63;
    const int h = lane >> 4, l15 = lane & 15;
    const size_t base = (size_t)n * 1024 * 384;
    const int qrowA = qt * 128 + w * 16 + l15;
    const float ts2 = temp[hd] * 1.44269504089f;
    const float nbound = -(fabsf(ts2) + 0.25f);

    bf16x8 qfA = *(const bf16x8*)(qkv + base + (size_t)qrowA * 384 + hd * 32 + h * 8);
    bf16x8 qfB = *(const bf16x8*)(qkv + base + (size_t)(qrowA + 64) * 384 + hd * 32 + h * 8);
    f32x4 oA0 = {0.f,0.f,0.f,0.f}, oA1 = {0.f,0.f,0.f,0.f};
    f32x4 oB0 = {0.f,0.f,0.f,0.f}, oB1 = {0.f,0.f,0.f,0.f};
    float psA = 0.f, psB = 0.f;

    const int skey = tid >> 2, sc4 = tid & 3;
    const int sg = skey >> 5, skey5 = skey & 31;
    const int sh = (skey5 >> 2) & 3;
    const int sj = (skey5 & 3) + ((skey5 >> 4) << 2);
    const int sgran0 = (sg * 4 + sh) * 32 + sc4 * 8;
    const short* kbase = qkv + base + (size_t)skey * 384 + 128 + hd * 32 + sc4 * 8;

    i32x4 kreg = *(const i32x4*)kbase;
    i32x4 vreg = *(const i32x4*)(kbase + 128);

    for (int t = 0; t < 16; ++t) {
        const int nb = t & 1;
        *(i32x4*)&Ks[nb][skey * 40 + sc4 * 8] = kreg;
        {
            short vs[8];
            *(i32x4*)vs = vreg;
#pragma unroll
            for (int i = 0; i < 8; ++i) {
                int gran = sgran0 + i;
                gran ^= (gran >> 3) & 7;
                Vp[nb][gran * 8 + sj] = vs[i];
            }
        }
        if (t < 15) {
            const short* kp = kbase + (size_t)(t + 1) * 64 * 384;
            kreg = *(const i32x4*)kp;
            vreg = *(const i32x4*)(kp + 128);
        }
        __syncthreads();

        const bf16x8 kf0 = *(const bf16x8*)&Ks[nb][l15 * 40 + h * 8];
        const bf16x8 kf1 = *(const bf16x8*)&Ks[nb][(16 + l15) * 40 + h * 8];
        const bf16x8 kf2 = *(const bf16x8*)&Ks[nb][(32 + l15) * 40 + h * 8];
        const bf16x8 kf3 = *(const bf16x8*)&Ks[nb][(48 + l15) * 40 + h * 8];
        int gr0 = h * 32 + l15;            gr0 ^= (gr0 >> 3) & 7;
        int gr1 = h * 32 + 16 + l15;       gr1 ^= (gr1 >> 3) & 7;
        int gr2 = (4 + h) * 32 + l15;      gr2 ^= (gr2 >> 3) & 7;
        int gr3 = (4 + h) * 32 + 16 + l15; gr3 ^= (gr3 >> 3) & 7;
        const bf16x8 va0 = *(const bf16x8*)&Vp[nb][gr0 * 8];
        const bf16x8 va1 = *(const bf16x8*)&Vp[nb][gr1 * 8];
        const bf16x8 vb0 = *(const bf16x8*)&Vp[nb][gr2 * 8];
        const bf16x8 vb1 = *(const bf16x8*)&Vp[nb][gr3 * 8];
        const f32x4 z = {0.f, 0.f, 0.f, 0.f};

        // ---- q-set A ----
        {
            f32x4 s0 = __builtin_amdgcn_mfma_f32_16x16x32_bf16(kf0, qfA, z, 0, 0, 0);
            f32x4 s1 = __builtin_amdgcn_mfma_f32_16x16x32_bf16(kf1, qfA, z, 0, 0, 0);
            f32x4 s2 = __builtin_amdgcn_mfma_f32_16x16x32_bf16(kf2, qfA, z, 0, 0, 0);
            f32x4 s3 = __builtin_amdgcn_mfma_f32_16x16x32_bf16(kf3, qfA, z, 0, 0, 0);
            float p[16];
#pragma unroll
            for (int r = 0; r < 4; ++r) {
                p[r]      = exp2f(fmaf(s0[r], ts2, nbound));
                p[4 + r]  = exp2f(fmaf(s1[r], ts2, nbound));
                p[8 + r]  = exp2f(fmaf(s2[r], ts2, nbound));
                p[12 + r] = exp2f(fmaf(s3[r], ts2, nbound));
            }
#pragma unroll
            for (int r = 0; r < 16; ++r) psA += p[r];
            union { unsigned u[4]; bf16x8 v; } pf1, pf2;
#pragma unroll
            for (int r = 0; r < 4; ++r) {
                pf1.u[r] = cvtpk(p[2 * r], p[2 * r + 1]);
                pf2.u[r] = cvtpk(p[8 + 2 * r], p[8 + 2 * r + 1]);
            }
            oA0 = __builtin_amdgcn_mfma_f32_16x16x32_bf16(va0, pf1.v, oA0, 0, 0, 0);
            oA1 = __builtin_amdgcn_mfma_f32_16x16x32_bf16(va1, pf1.v, oA1, 0, 0, 0);
            oA0 = __builtin_amdgcn_mfma_f32_16x16x32_bf16(vb0, pf2.v, oA0, 0, 0, 0);
            oA1 = __builtin_amdgcn_mfma_f32_16x16x32_bf16(vb1, pf2.v, oA1, 0, 0, 0);
        }
        // ---- q-set B ----
        {
            f32x4 s0 = __builtin_amdgcn_mfma_f32_16x16x32_bf16(kf0, qfB, z, 0, 0, 0);
            f32x4 s1 = __builtin_amdgcn_mfma_f32_16x16x32_bf16(kf1, qfB, z, 0, 0, 0);
            f32x4 s2 = __builtin_amdgcn_mfma_f32_16x16x32_bf16(kf2, qfB, z, 0, 0, 0);
            f32x4 s3 = __builtin_amdgcn_mfma_f32_16x16x32_bf16(kf3, qfB, z, 0, 0, 0);
            float p[16];
#pragma unroll
            for (int r = 0; r < 4; ++r) {
                p[r]      = exp2f(fmaf(s0[r], ts2, nbound));
                p[4 + r]  = exp2f(fmaf(s1[r], ts2, nbound));
                p[8 + r]  = exp2f(fmaf(s2[r], ts2, nbound));
                p[12 + r] = exp2f(fmaf(s3[r], ts2, nbound));
            }
#pragma unroll
            for (int r = 0; r < 16; ++r) psB += p[r];
            union { unsigned u[4]; bf16x8 v; } pf1, pf2;
#pragma unroll
            for (int r = 0; r < 4; ++r) {
                pf1.u[r] = cvtpk(p[2 * r], p[2 * r + 1]);
                pf2.u[r] = cvtpk(p[8 + 2 * r], p[8 + 2 * r + 1]);
            }
            oB0 = __builtin_amdgcn_mfma_f32_16x16x32_bf16(va0, pf1.v, oB0, 0, 0, 0);
            oB1 = __builtin_amdgcn_mfma_f32_16x16x32_bf16(va1, pf1.v, oB1, 0, 0, 0);
            oB0 = __builtin_amdgcn_mfma_f32_16x16x32_bf16(vb0, pf2.v, oB0, 0, 0, 0);
            oB1 = __builtin_amdgcn_mfma_f32_16x16x32_bf16(vb1, pf2.v, oB1, 0, 0, 0);
        }
    }

    psA += __shfl_xor(psA, 16); psA += __shfl_xor(psA, 32);
    psB += __shfl_xor(psB, 16); psB += __shfl_xor(psB, 32);
    float invA = 1.f / psA, invB = 1.f / psB;

    size_t obA = ((size_t)n * 1024 + qrowA) * 128 + hd * 32;
    size_t obB = obA + (size_t)64 * 128;
    unsigned u;
    u = f2b(oA0[0] * invA) | ((unsigned)f2b(oA0[1] * invA) << 16); *(unsigned*)(outp + obA + h * 4) = u;
    u = f2b(oA0[2] * invA) | ((unsigned)f2b(oA0[3] * invA) << 16); *(unsigned*)(outp + obA + h * 4 + 2) = u;
    u = f2b(oA1[0] * invA) | ((unsigned)f2b(oA1[1] * invA) << 16); *(unsigned*)(outp + obA + 16 + h * 4) = u;
    u = f2b(oA1[2] * invA) | ((unsigned)f2b(oA1[3] * invA) << 16); *(unsigned*)(outp + obA + 16 + h * 4 + 2) = u;
    u = f2b(oB0[0] * invB) | ((unsigned)f2b(oB0[1] * invB) << 16); *(unsigned*)(outp + obB + h * 4) = u;
    u = f2b(oB0[2] * invB) | ((unsigned)f2b(oB0[3] * invB) << 16); *(unsigned*)(outp + obB + h * 4 + 2) = u;
    u = f2b(oB1[0] * invB) | ((unsigned)f2b(oB1[1] * invB) << 16); *(unsigned*)(outp + obB + 16 + h * 4) = u;
    u = f2b(oB1[2] * invB) | ((unsigned)f2b(oB1[3] * invB) << 16); *(unsigned*)(outp + obB + 16 + h * 4 + 2) = u;
}

// ---------------------------------------------------------------------------
extern "C" void kernel_launch(void* const* d_in, const int* in_sizes, int n_in,
                              void* d_out, int out_size, void* d_ws, size_t ws_size,
                              hipStream_t stream) {
    const float* buffer      = (const float*)d_in[0];
    const float* mlp_w       = (const float*)d_in[1];
    const float* ln_attn_w   = (const float*)d_in[2];
    const float* ln_attn_b   = (const float*)d_in[3];
    const float* ln_ffn_w    = (const float*)d_in[4];
    const float* ln_ffn_b    = (const float*)d_in[5];
    const float* qkv_w       = (const float*)d_in[6];
    const float* qkv_dw_w    = (const float*)d_in[7];
    const float* temperature = (const float*)d_in[8];
    const float* proj_attn_w = (const float*)d_in[9];
    const float* ffn_in_w    = (const float*)d_in[10];
    const float* ffn_dw_w    = (const float*)d_in[11];
    const float* ffn_out_w   = (const float*)d_in[12];
    const float* proj3d_w    = (const float*)d_in[13];

    char* wsb = (char*)d_ws;
    short* Wbf     = (short*)wsb;                 // 287744 bf16 weights
    short* mlpW    = Wbf;                         // [128][640]
    short* qkvW    = Wbf + 81920;                 // [384][128]
    short* projW   = Wbf + 131072;                // [128][128]
    short* ffnInW  = Wbf + 147456;                // [680][128]
    short* ffnOutW = Wbf + 234496;                // [128][352] (padded)
    short* p3dW    = Wbf + 279552;                // [64][128]
    float* wqT     = (float*)(wsb + 575488);      // [9][384] f32
    float* wgT     = (float*)(wsb + 589312);      // [9][680] f32
    short* PatchB  = (short*)(wsb + 613792);      // [M][640] bf16
    float* tok     = (float*)(wsb + 33381792);    // [M][128] f32
    short* LNbf    = (short*)(wsb + 46488992);    // [M][128] bf16
    short* QKVpre  = (short*)(wsb + 53042592);    // [M][384] bf16
    short* qkvb    = (short*)(wsb + 72703392);    // [M][384] bf16
    short* AObf    = (short*)(wsb + 92364192);    // [M][128] bf16
    short* F1      = (short*)(wsb + 98917792);    // [M][680] bf16
    short* G       = (short*)(wsb + 133733792);   // [M][352] bf16 (padded)

    dim3 blk(256);

    cvtw_k<<<1124, blk, 0, stream>>>(mlp_w, qkv_w, proj_attn_w, ffn_in_w, ffn_out_w, proj3d_w, Wbf);
    twp_k<<<38, blk, 0, stream>>>(qkv_dw_w, ffn_dw_w, wqT, wgT);
    unfold_k<<<6400, blk, 0, stream>>>(buffer, PatchB);

    // S2T: tok = patches @ mlp_w^T (f32 out), K=640
    mm_k<false, false, false, false, 128, 640><<<dim3(200, 2), blk, 0, stream>>>(PatchB, mlpW, tok);
    ln_k<<<6400, blk, 0, stream>>>(tok, ln_attn_w, ln_attn_b, LNbf);
    // qkv 1x1 (bf16 out)
    mm_k<false, false, true, false, 384, 128><<<dim3(200, 6), blk, 0, stream>>>(LNbf, qkvW, QKVpre);
    // fused dwconv + l2norm
    dwl2n_k<<<4800, blk, 0, stream>>>(QKVpre, wqT, qkvb);
    // attention (round-5 proven kernel)
    attn_k<<<800, blk, 0, stream>>>(qkvb, temperature, AObf);
    // proj + residual
    mm_k<true, false, false, false, 128, 128><<<dim3(200, 2), blk, 0, stream>>>(AObf, projW, tok);
    ln_k<<<6400, blk, 0, stream>>>(tok, ln_ffn_w, ln_ffn_b, LNbf);
    // ffn_in 1x1 (bf16 out)
    mm_k<false, false, true, false, 680, 128><<<dim3(200, 11), blk, 0, stream>>>(LNbf, ffnInW, F1);
    // fused GDFN dwconv + gelu gate -> G [M][352] (padded)
    gdfn2_k<<<4400, blk, 0, stream>>>(F1, wgT, G);
    // ffn_out + residual, K=352 (both sides zero-padded)
    mm_k<true, false, false, false, 128, 352><<<dim3(200, 2), blk, 0, stream>>>(G, ffnOutW, tok);
    // Token2SAI (transposed product, coalesced)
    mm_k<false, true, false, true, 64, 128><<<dim3(200, 1), blk, 0, stream>>>(tok, p3dW, d_out);
}

// Round 10
// 251.782 us; speedup vs baseline: 1.1115x; 1.0907x over previous
//
#include <hip/hip_runtime.h>
#include <math.h>

#define M_TOK 25600   // 25 images * 1024 tokens

typedef __attribute__((ext_vector_type(8))) short bf16x8;
typedef __attribute__((ext_vector_type(4))) float f32x4;
typedef __attribute__((ext_vector_type(4))) int   i32x4;
typedef __attribute__((ext_vector_type(2))) int   i32x2;

__device__ __forceinline__ unsigned short f2b(float x) {
    unsigned u = __builtin_bit_cast(unsigned, x);
    return (unsigned short)((u + 0x7fffu + ((u >> 16) & 1u)) >> 16);
}
__device__ __forceinline__ float b2f(unsigned short h) {
    unsigned u = ((unsigned)h) << 16;
    return __builtin_bit_cast(float, u);
}
__device__ __forceinline__ unsigned cvtpk(float lo, float hi) {
    unsigned r;
    asm("v_cvt_pk_bf16_f32 %0, %1, %2" : "=v"(r) : "v"(lo), "v"(hi));
    return r;
}

// ---------------------------------------------------------------------------
// Merged prep: weight fp32->bf16 (round-5 layout) + depthwise-weight
// transposes. i < 286208: bf16 weights; else: wqT/wgT f32 transposes.
// ---------------------------------------------------------------------------
__global__ __launch_bounds__(256) void prep_k(const float* __restrict__ s0, const float* __restrict__ s1,
                                              const float* __restrict__ s2, const float* __restrict__ s3,
                                              const float* __restrict__ s4, const float* __restrict__ s5,
                                              const float* __restrict__ qw, const float* __restrict__ fw,
                                              short* __restrict__ dst,
                                              float* __restrict__ wqT, float* __restrict__ wgT) {
    int i = blockIdx.x * 256 + threadIdx.x;      // < 295784
    if (i >= 295784) return;
    if (i < 286208) {
        if (i < 81920) {
            int tap = i % 10, q = i / 10;        // mlp_w -> [128][64][10], tap 9 zero
            dst[i] = (tap < 9) ? (short)f2b(s0[q * 9 + tap]) : (short)0;
            return;
        }
        const float* s; int off;
        if      (i < 131072) { s = s1; off = i - 81920; }
        else if (i < 147456) { s = s2; off = i - 131072; }
        else if (i < 234496) { s = s3; off = i - 147456; }
        else if (i < 278016) { s = s4; off = i - 234496; }
        else                 { s = s5; off = i - 278016; }
        dst[i] = (short)f2b(s[off]);
        return;
    }
    int j = i - 286208;                          // < 9576
    if (j < 3456) {
        int tap = j / 384, c = j % 384;
        wqT[j] = qw[c * 9 + tap];
    } else {
        int k = j - 3456;
        int tap = k / 680, c = k % 680;
        wgT[k] = fw[c * 9 + tap];
    }
}

// ---------------------------------------------------------------------------
// im2col 3x3 (zero pad) -> bf16 patch matrix [M][640]: col = cc*10 + tap.
// ---------------------------------------------------------------------------
__global__ __launch_bounds__(256) void unfold_k(const float* __restrict__ buf, short* __restrict__ P) {
    int idx = blockIdx.x * 256 + threadIdx.x;    // < M*64
    int cc = idx & 63;
    int t  = idx >> 6;
    int l = t & 1023, n = t >> 10;
    int y = l >> 5, x = l & 31;
    const float* src = buf + (size_t)cc * M_TOK + (n << 10);
    float v[9];
#pragma unroll
    for (int ti = 0; ti < 3; ++ti) {
        int yy = y + ti - 1;
        bool yok = (yy >= 0 && yy < 32);
#pragma unroll
        for (int tj = 0; tj < 3; ++tj) {
            int xx = x + tj - 1;
            v[ti * 3 + tj] = (yok && xx >= 0 && xx < 32) ? src[(yy << 5) + xx] : 0.f;
        }
    }
    unsigned* dst = (unsigned*)(P + (size_t)t * 640 + cc * 10);
    dst[0] = f2b(v[0]) | ((unsigned)f2b(v[1]) << 16);
    dst[1] = f2b(v[2]) | ((unsigned)f2b(v[3]) << 16);
    dst[2] = f2b(v[4]) | ((unsigned)f2b(v[5]) << 16);
    dst[3] = f2b(v[6]) | ((unsigned)f2b(v[7]) << 16);
    dst[4] = (unsigned)f2b(v[8]);
}

// ---------------------------------------------------------------------------
// bf16 MFMA GEMM, BK=64: out[M x N] (+=) A[M x K(lda)] * W[N x K]^T
// 128x64 tile, 4 waves (2x2). Per phase: stage 64 k, 1 barrier pair,
// 2 MFMA k-substeps (16 MFMAs/wave) -> half the barriers of BK=32.
// ---------------------------------------------------------------------------
template <bool ADD, bool TROUT, bool OUTBF16, bool AF32>
__global__ __launch_bounds__(256) void mm_k(const void* __restrict__ Avp,
                                            const short* __restrict__ W,
                                            void* __restrict__ outp,
                                            int M, int N, int K, int lda) {
    __shared__ __align__(16) short As[128 * 72];
    __shared__ __align__(16) short Bs[64 * 72];
    const int tid = threadIdx.x;
    const int bm = blockIdx.x * 128;
    const int bn = blockIdx.y * 64;
    const int w = tid >> 6, lane = tid & 63;
    const int h = lane >> 4, l15 = lane & 15;
    const int wm = (w >> 1) * 64, wn = (w & 1) * 32;

    f32x4 acc[4][2];
#pragma unroll
    for (int i = 0; i < 4; ++i)
#pragma unroll
        for (int j = 0; j < 2; ++j) acc[i][j] = (f32x4){0.f, 0.f, 0.f, 0.f};

    for (int k0 = 0; k0 < K; k0 += 64) {
        // stage A: 128 rows x 64 k = 1024 chunks of 8 bf16
#pragma unroll
        for (int e = 0; e < 4; ++e) {
            int li = tid + e * 256;
            int row = li >> 3, c8 = li & 7;
            int gk = k0 + c8 * 8;
            size_t abase = (size_t)(bm + row) * lda + gk;
            short tmp[8];
            if (AF32) {
                const float* ap = (const float*)Avp + abase;
                if (gk + 8 <= K) {
                    float4 va = *(const float4*)ap;
                    float4 vb = *(const float4*)(ap + 4);
                    tmp[0] = (short)f2b(va.x); tmp[1] = (short)f2b(va.y);
                    tmp[2] = (short)f2b(va.z); tmp[3] = (short)f2b(va.w);
                    tmp[4] = (short)f2b(vb.x); tmp[5] = (short)f2b(vb.y);
                    tmp[6] = (short)f2b(vb.z); tmp[7] = (short)f2b(vb.w);
                } else {
#pragma unroll
                    for (int i = 0; i < 8; ++i) tmp[i] = (gk + i < K) ? (short)f2b(ap[i]) : (short)0;
                }
            } else {
                const short* ap = (const short*)Avp + abase;
                if (gk + 8 <= K) {
                    i32x2 a = *(const i32x2*)ap;
                    i32x2 b = *(const i32x2*)(ap + 4);
                    *(i32x2*)&tmp[0] = a; *(i32x2*)&tmp[4] = b;
                } else {
#pragma unroll
                    for (int i = 0; i < 8; ++i) tmp[i] = (gk + i < K) ? ap[i] : (short)0;
                }
            }
            *(i32x4*)&As[row * 72 + c8 * 8] = *(i32x4*)tmp;
        }
        // stage W: 64 rows x 64 k = 512 chunks
#pragma unroll
        for (int e = 0; e < 2; ++e) {
            int li = tid + e * 256;
            int row = li >> 3, c8 = li & 7;
            int gk = k0 + c8 * 8;
            int gn = bn + row;
            short tmp[8];
            if (gn < N && gk + 8 <= K) {
                const short* wp = W + (size_t)gn * K + gk;
                i32x2 a = *(const i32x2*)wp;
                i32x2 b = *(const i32x2*)(wp + 4);
                *(i32x2*)&tmp[0] = a; *(i32x2*)&tmp[4] = b;
            } else {
#pragma unroll
                for (int i = 0; i < 8; ++i)
                    tmp[i] = (gn < N && gk + i < K) ? W[(size_t)gn * K + gk + i] : (short)0;
            }
            *(i32x4*)&Bs[row * 72 + c8 * 8] = *(i32x4*)tmp;
        }
        __syncthreads();
#pragma unroll
        for (int kk = 0; kk < 2; ++kk) {
            bf16x8 af[4], bf[2];
#pragma unroll
            for (int mi = 0; mi < 4; ++mi)
                af[mi] = *(const bf16x8*)&As[(wm + mi * 16 + l15) * 72 + kk * 32 + h * 8];
#pragma unroll
            for (int nj = 0; nj < 2; ++nj)
                bf[nj] = *(const bf16x8*)&Bs[(wn + nj * 16 + l15) * 72 + kk * 32 + h * 8];
#pragma unroll
            for (int mi = 0; mi < 4; ++mi)
#pragma unroll
                for (int nj = 0; nj < 2; ++nj) {
                    if (TROUT)
                        acc[mi][nj] = __builtin_amdgcn_mfma_f32_16x16x32_bf16(bf[nj], af[mi], acc[mi][nj], 0, 0, 0);
                    else
                        acc[mi][nj] = __builtin_amdgcn_mfma_f32_16x16x32_bf16(af[mi], bf[nj], acc[mi][nj], 0, 0, 0);
                }
        }
        __syncthreads();
    }

    if (!TROUT) {
#pragma unroll
        for (int mi = 0; mi < 4; ++mi) {
#pragma unroll
            for (int nj = 0; nj < 2; ++nj) {
                int gn = bn + wn + nj * 16 + l15;
                if (gn < N) {
#pragma unroll
                    for (int r = 0; r < 4; ++r) {
                        int gm = bm + wm + mi * 16 + h * 4 + r;
                        float v = acc[mi][nj][r];
                        size_t oi = (size_t)gm * N + gn;
                        if (OUTBF16)      ((short*)outp)[oi] = (short)f2b(v);
                        else if (ADD)     ((float*)outp)[oi] += v;
                        else              ((float*)outp)[oi] = v;
                    }
                }
            }
        }
    } else {
#pragma unroll
        for (int mi = 0; mi < 4; ++mi) {
            int gm = bm + wm + mi * 16 + l15;
#pragma unroll
            for (int nj = 0; nj < 2; ++nj)
#pragma unroll
                for (int r = 0; r < 4; ++r) {
                    int gn = bn + wn + nj * 16 + h * 4 + r;
                    if (gn < N) ((float*)outp)[(size_t)gn * M + gm] = acc[mi][nj][r];
                }
        }
    }
}

// ---------------------------------------------------------------------------
// LayerNorm D=128, fp32 in -> bf16 out.
// ---------------------------------------------------------------------------
__global__ __launch_bounds__(256) void ln_k(const float* __restrict__ in,
                                            const float* __restrict__ w,
                                            const float* __restrict__ b,
                                            short* __restrict__ out) {
    int t = blockIdx.x * 4 + (threadIdx.x >> 6);
    int lane = threadIdx.x & 63;
    float2 v = *(const float2*)(in + (size_t)t * 128 + lane * 2);
    float s = v.x + v.y, sq = v.x * v.x + v.y * v.y;
#pragma unroll
    for (int off = 32; off > 0; off >>= 1) { s += __shfl_xor(s, off); sq += __shfl_xor(sq, off); }
    float mean = s * (1.f / 128.f);
    float var = sq * (1.f / 128.f) - mean * mean;
    float rstd = rsqrtf(var + 1e-5f);
    float2 wv = *(const float2*)(w + lane * 2);
    float2 bv = *(const float2*)(b + lane * 2);
    float ox = (v.x - mean) * rstd * wv.x + bv.x;
    float oy = (v.y - mean) * rstd * wv.y + bv.y;
    ((unsigned*)out)[(size_t)t * 64 + lane] = f2b(ox) | ((unsigned)f2b(oy) << 16);
}

// ---------------------------------------------------------------------------
// Fused qkv depthwise 3x3 + l2norm(q,k heads).
// ---------------------------------------------------------------------------
__global__ __launch_bounds__(256) void dwl2n_k(const short* __restrict__ in,
                                               const float* __restrict__ wqT,
                                               short* __restrict__ out) {
    int idx = blockIdx.x * 256 + threadIdx.x;    // < M*48
    int q = idx % 48;
    int t = idx / 48;
    int c0 = q * 8;
    int l = t & 1023, n = t >> 10;
    int y = l >> 5, x = l & 31;
    int tb = n << 10;

    float acc[8];
#pragma unroll
    for (int k = 0; k < 8; ++k) acc[k] = 0.f;

#pragma unroll
    for (int i = 0; i < 3; ++i) {
        int yy = y + i - 1;
        if (yy < 0 || yy >= 32) continue;
#pragma unroll
        for (int j = 0; j < 3; ++j) {
            int xx = x + j - 1;
            if (xx < 0 || xx >= 32) continue;
            bf16x8 d = *(const bf16x8*)(in + (size_t)(tb + (yy << 5) + xx) * 384 + c0);
            float4 wa = *(const float4*)(wqT + (i * 3 + j) * 384 + c0);
            float4 wb = *(const float4*)(wqT + (i * 3 + j) * 384 + c0 + 4);
            acc[0] += b2f((unsigned short)d[0]) * wa.x;
            acc[1] += b2f((unsigned short)d[1]) * wa.y;
            acc[2] += b2f((unsigned short)d[2]) * wa.z;
            acc[3] += b2f((unsigned short)d[3]) * wa.w;
            acc[4] += b2f((unsigned short)d[4]) * wb.x;
            acc[5] += b2f((unsigned short)d[5]) * wb.y;
            acc[6] += b2f((unsigned short)d[6]) * wb.z;
            acc[7] += b2f((unsigned short)d[7]) * wb.w;
        }
    }
    float ss = 0.f;
#pragma unroll
    for (int k = 0; k < 8; ++k) ss += acc[k] * acc[k];
    ss += __shfl_xor(ss, 1);
    ss += __shfl_xor(ss, 2);
    float sc = (c0 < 256) ? (1.f / fmaxf(sqrtf(ss), 1e-12f)) : 1.f;
    unsigned o[4];
#pragma unroll
    for (int k = 0; k < 4; ++k)
        o[k] = f2b(acc[2 * k] * sc) | ((unsigned)f2b(acc[2 * k + 1] * sc) << 16);
    *(i32x4*)(out + (size_t)t * 384 + c0) = *(i32x4*)o;
}

// ---------------------------------------------------------------------------
// Fused GDFN depthwise (round-5 version, out lda = 344).
// ---------------------------------------------------------------------------
__global__ __launch_bounds__(256) void gdfn2_k(const short* __restrict__ in,
                                               const float* __restrict__ wgT,
                                               short* __restrict__ out) {
    int idx = blockIdx.x * 256 + threadIdx.x;    // < M*43
    int q = idx % 43;
    int t = idx / 43;
    int c0 = q * 8;
    int l = t & 1023, n = t >> 10;
    int y = l >> 5, x = l & 31;
    int tb = n << 10;

    float a[8], g[8];
#pragma unroll
    for (int k = 0; k < 8; ++k) { a[k] = 0.f; g[k] = 0.f; }

#pragma unroll
    for (int i = 0; i < 3; ++i) {
        int yy = y + i - 1;
        if (yy < 0 || yy >= 32) continue;
#pragma unroll
        for (int j = 0; j < 3; ++j) {
            int xx = x + j - 1;
            if (xx < 0 || xx >= 32) continue;
            const short* p = in + (size_t)(tb + (yy << 5) + xx) * 680 + c0;
            bf16x8 d1 = *(const bf16x8*)p;
            i32x2 d2a = *(const i32x2*)(p + 340);
            i32x2 d2b = *(const i32x2*)(p + 344);
            short d2[8];
            *(i32x2*)&d2[0] = d2a; *(i32x2*)&d2[4] = d2b;
            const float* wp = wgT + (i * 3 + j) * 680 + c0;
            float4 w1a = *(const float4*)wp;
            float4 w1b = *(const float4*)(wp + 4);
            float w1[8] = {w1a.x, w1a.y, w1a.z, w1a.w, w1b.x, w1b.y, w1b.z, w1b.w};
            float w2[8];
#pragma unroll
            for (int k = 0; k < 8; ++k) w2[k] = wp[340 + k];
#pragma unroll
            for (int k = 0; k < 8; ++k) {
                a[k] += b2f((unsigned short)d1[k]) * w1[k];
                g[k] += b2f((unsigned short)d2[k]) * w2[k];
            }
        }
    }
    unsigned o[4];
#pragma unroll
    for (int k = 0; k < 4; ++k) {
        float r0 = 0.5f * a[2 * k] * (1.f + erff(a[2 * k] * 0.70710678118f)) * g[2 * k];
        float r1 = 0.5f * a[2 * k + 1] * (1.f + erff(a[2 * k + 1] * 0.70710678118f)) * g[2 * k + 1];
        o[k] = f2b(r0) | ((unsigned)f2b(r1) << 16);
    }
    short* op = out + (size_t)t * 344 + c0;
    if (q < 42) *(i32x4*)op = *(i32x4*)o;
    else        *(i32x2*)op = (i32x2){(int)o[0], (int)o[1]};
}

// ---------------------------------------------------------------------------
// MFMA flash attention v5: round-5 proven structure (LDS K+Vp double-buffer,
// one barrier/tile, register prefetch, zero-shuffle PV, fixed-bound softmax)
// simplified to 64 q-rows/block x 1600 blocks for 2x waves/SIMD (TLP).
// ---------------------------------------------------------------------------
__global__ __launch_bounds__(256) void attn_k(const short* __restrict__ qkv,
                                              const float* __restrict__ temp,
                                              short* __restrict__ outp) {
    __shared__ __align__(16) short Ks[2][64 * 40];
    __shared__ __align__(16) short Vp[2][2048];
    const int bid = blockIdx.x;              // 1600 = nh*16 + qt
    const int qt = bid & 15, nh = bid >> 4;
    const int hd = nh & 3, n = nh >> 2;
    const int tid = threadIdx.x;
    const int w = tid >> 6, lane = tid & 63;
    const int h = lane >> 4, l15 = lane & 15;
    const size_t base = (size_t)n * 1024 * 384;
    const int qrow = qt * 64 + w * 16 + l15;
    const float ts2 = temp[hd] * 1.44269504089f;       // exp2-domain temperature
    const float nbound = -(fabsf(ts2) + 0.25f);        // static softmax shift

    bf16x8 qf = *(const bf16x8*)(qkv + base + (size_t)qrow * 384 + hd * 32 + h * 8);
    f32x4 o0 = {0.f,0.f,0.f,0.f}, o1 = {0.f,0.f,0.f,0.f};
    float ps = 0.f;

    // staging coords: thread -> (key, c4); V permuted to PV B-frag slot order
    const int skey = tid >> 2, sc4 = tid & 3;
    const int sg = skey >> 5, skey5 = skey & 31;
    const int sh = (skey5 >> 2) & 3;
    const int sj = (skey5 & 3) + ((skey5 >> 4) << 2);
    const int sgran0 = (sg * 4 + sh) * 32 + sc4 * 8;
    const short* kbase = qkv + base + (size_t)skey * 384 + 128 + hd * 32 + sc4 * 8;

    i32x4 kreg = *(const i32x4*)kbase;
    i32x4 vreg = *(const i32x4*)(kbase + 128);

    for (int t = 0; t < 16; ++t) {
        const int nb = t & 1;
        *(i32x4*)&Ks[nb][skey * 40 + sc4 * 8] = kreg;
        {
            short vs[8];
            *(i32x4*)vs = vreg;
#pragma unroll
            for (int i = 0; i < 8; ++i) {
                int gran = sgran0 + i;
                gran ^= (gran >> 3) & 7;
                Vp[nb][gran * 8 + sj] = vs[i];
            }
        }
        if (t < 15) {
            const short* kp = kbase + (size_t)(t + 1) * 64 * 384;
            kreg = *(const i32x4*)kp;
            vreg = *(const i32x4*)(kp + 128);
        }
        __syncthreads();

        const bf16x8 kf0 = *(const bf16x8*)&Ks[nb][l15 * 40 + h * 8];
        const bf16x8 kf1 = *(const bf16x8*)&Ks[nb][(16 + l15) * 40 + h * 8];
        const bf16x8 kf2 = *(const bf16x8*)&Ks[nb][(32 + l15) * 40 + h * 8];
        const bf16x8 kf3 = *(const bf16x8*)&Ks[nb][(48 + l15) * 40 + h * 8];
        int gr0 = h * 32 + l15;            gr0 ^= (gr0 >> 3) & 7;
        int gr1 = h * 32 + 16 + l15;       gr1 ^= (gr1 >> 3) & 7;
        int gr2 = (4 + h) * 32 + l15;      gr2 ^= (gr2 >> 3) & 7;
        int gr3 = (4 + h) * 32 + 16 + l15; gr3 ^= (gr3 >> 3) & 7;
        const bf16x8 va0 = *(const bf16x8*)&Vp[nb][gr0 * 8];
        const bf16x8 va1 = *(const bf16x8*)&Vp[nb][gr1 * 8];
        const bf16x8 vb0 = *(const bf16x8*)&Vp[nb][gr2 * 8];
        const bf16x8 vb1 = *(const bf16x8*)&Vp[nb][gr3 * 8];
        const f32x4 z = {0.f, 0.f, 0.f, 0.f};

        f32x4 s0 = __builtin_amdgcn_mfma_f32_16x16x32_bf16(kf0, qf, z, 0, 0, 0);
        f32x4 s1 = __builtin_amdgcn_mfma_f32_16x16x32_bf16(kf1, qf, z, 0, 0, 0);
        f32x4 s2 = __builtin_amdgcn_mfma_f32_16x16x32_bf16(kf2, qf, z, 0, 0, 0);
        f32x4 s3 = __builtin_amdgcn_mfma_f32_16x16x32_bf16(kf3, qf, z, 0, 0, 0);
        float p[16];
#pragma unroll
        for (int r = 0; r < 4; ++r) {
            p[r]      = exp2f(fmaf(s0[r], ts2, nbound));
            p[4 + r]  = exp2f(fmaf(s1[r], ts2, nbound));
            p[8 + r]  = exp2f(fmaf(s2[r], ts2, nbound));
            p[12 + r] = exp2f(fmaf(s3[r], ts2, nbound));
        }
#pragma unroll
        for (int r = 0; r < 16; ++r) ps += p[r];
        union { unsigned u[4]; bf16x8 v; } pf1, pf2;
#pragma unroll
        for (int r = 0; r < 4; ++r) {
            pf1.u[r] = cvtpk(p[2 * r], p[2 * r + 1]);
            pf2.u[r] = cvtpk(p[8 + 2 * r], p[8 + 2 * r + 1]);
        }
        o0 = __builtin_amdgcn_mfma_f32_16x16x32_bf16(va0, pf1.v, o0, 0, 0, 0);
        o1 = __builtin_amdgcn_mfma_f32_16x16x32_bf16(va1, pf1.v, o1, 0, 0, 0);
        o0 = __builtin_amdgcn_mfma_f32_16x16x32_bf16(vb0, pf2.v, o0, 0, 0, 0);
        o1 = __builtin_amdgcn_mfma_f32_16x16x32_bf16(vb1, pf2.v, o1, 0, 0, 0);
    }

    ps += __shfl_xor(ps, 16);
    ps += __shfl_xor(ps, 32);
    float inv = 1.f / ps;

    size_t ob = ((size_t)n * 1024 + qrow) * 128 + hd * 32;
    unsigned u;
    u = f2b(o0[0] * inv) | ((unsigned)f2b(o0[1] * inv) << 16); *(unsigned*)(outp + ob + h * 4) = u;
    u = f2b(o0[2] * inv) | ((unsigned)f2b(o0[3] * inv) << 16); *(unsigned*)(outp + ob + h * 4 + 2) = u;
    u = f2b(o1[0] * inv) | ((unsigned)f2b(o1[1] * inv) << 16); *(unsigned*)(outp + ob + 16 + h * 4) = u;
    u = f2b(o1[2] * inv) | ((unsigned)f2b(o1[3] * inv) << 16); *(unsigned*)(outp + ob + 16 + h * 4 + 2) = u;
}

// ---------------------------------------------------------------------------
extern "C" void kernel_launch(void* const* d_in, const int* in_sizes, int n_in,
                              void* d_out, int out_size, void* d_ws, size_t ws_size,
                              hipStream_t stream) {
    const float* buffer      = (const float*)d_in[0];
    const float* mlp_w       = (const float*)d_in[1];
    const float* ln_attn_w   = (const float*)d_in[2];
    const float* ln_attn_b   = (const float*)d_in[3];
    const float* ln_ffn_w    = (const float*)d_in[4];
    const float* ln_ffn_b    = (const float*)d_in[5];
    const float* qkv_w       = (const float*)d_in[6];
    const float* qkv_dw_w    = (const float*)d_in[7];
    const float* temperature = (const float*)d_in[8];
    const float* proj_attn_w = (const float*)d_in[9];
    const float* ffn_in_w    = (const float*)d_in[10];
    const float* ffn_dw_w    = (const float*)d_in[11];
    const float* ffn_out_w   = (const float*)d_in[12];
    const float* proj3d_w    = (const float*)d_in[13];

    char* wsb = (char*)d_ws;
    short* Wbf     = (short*)wsb;                 // 286208 bf16 weights (round-5 layout)
    short* mlpW    = Wbf;                         // [128][640]
    short* qkvW    = Wbf + 81920;                 // [384][128]
    short* projW   = Wbf + 131072;                // [128][128]
    short* ffnInW  = Wbf + 147456;                // [680][128]
    short* ffnOutW = Wbf + 234496;                // [128][340]
    short* p3dW    = Wbf + 278016;                // [64][128]
    float* wqT     = (float*)(wsb + 573440);      // [9][384] f32
    float* wgT     = (float*)(wsb + 587264);      // [9][680] f32
    short* PatchB  = (short*)(wsb + 611840);      // [M][640] bf16
    float* tok     = (float*)(wsb + 33379840);    // [M][128] f32
    short* LNbf    = (short*)(wsb + 46487040);    // [M][128] bf16
    short* QKVpre  = (short*)(wsb + 53040640);    // [M][384] bf16
    short* qkvb    = (short*)(wsb + 72701440);    // [M][384] bf16
    short* AObf    = (short*)(wsb + 92362240);    // [M][128] bf16
    short* F1      = (short*)(wsb + 98915840);    // [M][680] bf16
    short* G       = (short*)(wsb + 133731840);   // [M][344] bf16 (lda 344)

    dim3 blk(256);

    prep_k<<<1156, blk, 0, stream>>>(mlp_w, qkv_w, proj_attn_w, ffn_in_w, ffn_out_w, proj3d_w,
                                     qkv_dw_w, ffn_dw_w, Wbf, wqT, wgT);
    unfold_k<<<6400, blk, 0, stream>>>(buffer, PatchB);

    // S2T: tok = patches @ mlp_w^T (f32 out), K padded to 640
    mm_k<false, false, false, false><<<dim3(200, 2), blk, 0, stream>>>(PatchB, mlpW, tok, M_TOK, 128, 640, 640);
    ln_k<<<6400, blk, 0, stream>>>(tok, ln_attn_w, ln_attn_b, LNbf);
    // qkv 1x1 (bf16 out)
    mm_k<false, false, true, false><<<dim3(200, 6), blk, 0, stream>>>(LNbf, qkvW, QKVpre, M_TOK, 384, 128, 128);
    // fused dwconv + l2norm
    dwl2n_k<<<4800, blk, 0, stream>>>(QKVpre, wqT, qkvb);
    // attention (v5: 64 q-rows/block, 1600 blocks)
    attn_k<<<1600, blk, 0, stream>>>(qkvb, temperature, AObf);
    // proj + residual
    mm_k<true, false, false, false><<<dim3(200, 2), blk, 0, stream>>>(AObf, projW, tok, M_TOK, 128, 128, 128);
    ln_k<<<6400, blk, 0, stream>>>(tok, ln_ffn_w, ln_ffn_b, LNbf);
    // ffn_in 1x1 (bf16 out)
    mm_k<false, false, true, false><<<dim3(200, 11), blk, 0, stream>>>(LNbf, ffnInW, F1, M_TOK, 680, 128, 128);
    // fused GDFN dwconv + gelu gate
    gdfn2_k<<<4300, blk, 0, stream>>>(F1, wgT, G);
    // ffn_out + residual (A lda = 344)
    mm_k<true, false, false, false><<<dim3(200, 2), blk, 0, stream>>>(G, ffnOutW, tok, M_TOK, 128, 340, 344);
    // Token2SAI (transposed product, coalesced)
    mm_k<false, true, false, true><<<dim3(200, 1), blk, 0, stream>>>(tok, p3dW, d_out, M_TOK, 64, 128, 128);
}

// Round 11
// 231.329 us; speedup vs baseline: 1.2098x; 1.0884x over previous
//
#include <hip/hip_runtime.h>
#include <math.h>

#define M_TOK 25600   // 25 images * 1024 tokens

typedef __attribute__((ext_vector_type(8))) short bf16x8;
typedef __attribute__((ext_vector_type(4))) float f32x4;
typedef __attribute__((ext_vector_type(4))) int   i32x4;
typedef __attribute__((ext_vector_type(2))) int   i32x2;

__device__ __forceinline__ unsigned short f2b(float x) {
    unsigned u = __builtin_bit_cast(unsigned, x);
    return (unsigned short)((u + 0x7fffu + ((u >> 16) & 1u)) >> 16);
}
__device__ __forceinline__ float b2f(unsigned short h) {
    unsigned u = ((unsigned)h) << 16;
    return __builtin_bit_cast(float, u);
}
__device__ __forceinline__ unsigned cvtpk(float lo, float hi) {
    unsigned r;
    asm("v_cvt_pk_bf16_f32 %0, %1, %2" : "=v"(r) : "v"(lo), "v"(hi));
    return r;
}

// ---------------------------------------------------------------------------
// Merged prep: weight fp32->bf16 (round-5 layout) + depthwise-weight
// transposes. i < 286208: bf16 weights; else: wqT/wgT f32 transposes.
// ---------------------------------------------------------------------------
__global__ __launch_bounds__(256) void prep_k(const float* __restrict__ s0, const float* __restrict__ s1,
                                              const float* __restrict__ s2, const float* __restrict__ s3,
                                              const float* __restrict__ s4, const float* __restrict__ s5,
                                              const float* __restrict__ qw, const float* __restrict__ fw,
                                              short* __restrict__ dst,
                                              float* __restrict__ wqT, float* __restrict__ wgT) {
    int i = blockIdx.x * 256 + threadIdx.x;      // < 295784
    if (i >= 295784) return;
    if (i < 286208) {
        if (i < 81920) {
            int tap = i % 10, q = i / 10;        // mlp_w -> [128][64][10], tap 9 zero
            dst[i] = (tap < 9) ? (short)f2b(s0[q * 9 + tap]) : (short)0;
            return;
        }
        const float* s; int off;
        if      (i < 131072) { s = s1; off = i - 81920; }
        else if (i < 147456) { s = s2; off = i - 131072; }
        else if (i < 234496) { s = s3; off = i - 147456; }
        else if (i < 278016) { s = s4; off = i - 234496; }
        else                 { s = s5; off = i - 278016; }
        dst[i] = (short)f2b(s[off]);
        return;
    }
    int j = i - 286208;                          // < 9576
    if (j < 3456) {
        int tap = j / 384, c = j % 384;
        wqT[j] = qw[c * 9 + tap];
    } else {
        int k = j - 3456;
        int tap = k / 680, c = k % 680;
        wgT[k] = fw[c * 9 + tap];
    }
}

// ---------------------------------------------------------------------------
// im2col 3x3 (zero pad) -> bf16 patch matrix [M][640]: col = cc*10 + tap.
// ---------------------------------------------------------------------------
__global__ __launch_bounds__(256) void unfold_k(const float* __restrict__ buf, short* __restrict__ P) {
    int idx = blockIdx.x * 256 + threadIdx.x;    // < M*64
    int cc = idx & 63;
    int t  = idx >> 6;
    int l = t & 1023, n = t >> 10;
    int y = l >> 5, x = l & 31;
    const float* src = buf + (size_t)cc * M_TOK + (n << 10);
    float v[9];
#pragma unroll
    for (int ti = 0; ti < 3; ++ti) {
        int yy = y + ti - 1;
        bool yok = (yy >= 0 && yy < 32);
#pragma unroll
        for (int tj = 0; tj < 3; ++tj) {
            int xx = x + tj - 1;
            v[ti * 3 + tj] = (yok && xx >= 0 && xx < 32) ? src[(yy << 5) + xx] : 0.f;
        }
    }
    unsigned* dst = (unsigned*)(P + (size_t)t * 640 + cc * 10);
    dst[0] = f2b(v[0]) | ((unsigned)f2b(v[1]) << 16);
    dst[1] = f2b(v[2]) | ((unsigned)f2b(v[3]) << 16);
    dst[2] = f2b(v[4]) | ((unsigned)f2b(v[5]) << 16);
    dst[3] = f2b(v[6]) | ((unsigned)f2b(v[7]) << 16);
    dst[4] = (unsigned)f2b(v[8]);
}

// ---------------------------------------------------------------------------
// bf16 MFMA GEMM v3: BK=32, DOUBLE-BUFFERED LDS, ONE barrier per phase,
// register prefetch of phase k0+32 (global loads in flight across barrier).
// out[M x N] (+=) A[M x K(lda)] * W[N x K]^T. 128x64 tile, 4 waves (2x2).
// ---------------------------------------------------------------------------
template <bool ADD, bool TROUT, bool OUTBF16, bool AF32>
__global__ __launch_bounds__(256) void mm_k(const void* __restrict__ Avp,
                                            const short* __restrict__ W,
                                            void* __restrict__ outp,
                                            int M, int N, int K, int lda) {
    __shared__ __align__(16) short As[2][128 * 40];
    __shared__ __align__(16) short Bs[2][64 * 40];
    const int tid = threadIdx.x;
    const int bm = blockIdx.x * 128;
    const int bn = blockIdx.y * 64;
    const int w = tid >> 6, lane = tid & 63;
    const int h = lane >> 4, l15 = lane & 15;
    const int wm = (w >> 1) * 64, wn = (w & 1) * 32;

    const int rowA0 = tid >> 2, c4 = tid & 3;    // A chunk 0: rows 0..63
    const int rowA1 = rowA0 + 64;                // A chunk 1: rows 64..127
    const int gnW = bn + rowA0;                  // W row (0..63)

    f32x4 acc[4][2];
#pragma unroll
    for (int i = 0; i < 4; ++i)
#pragma unroll
        for (int j = 0; j < 2; ++j) acc[i][j] = (f32x4){0.f, 0.f, 0.f, 0.f};

    short a0[8], a1[8], wv[8];

    // ---- staging loaders (into registers) ----
    auto ldA = [&](int row, int k0, short* tmp) {
        int gk = k0 + c4 * 8;
        size_t abase = (size_t)(bm + row) * lda + gk;
        if (AF32) {
            const float* ap = (const float*)Avp + abase;
            if (gk + 8 <= K) {
                float4 va = *(const float4*)ap;
                float4 vb = *(const float4*)(ap + 4);
                tmp[0] = (short)f2b(va.x); tmp[1] = (short)f2b(va.y);
                tmp[2] = (short)f2b(va.z); tmp[3] = (short)f2b(va.w);
                tmp[4] = (short)f2b(vb.x); tmp[5] = (short)f2b(vb.y);
                tmp[6] = (short)f2b(vb.z); tmp[7] = (short)f2b(vb.w);
            } else {
#pragma unroll
                for (int i = 0; i < 8; ++i) tmp[i] = (gk + i < K) ? (short)f2b(ap[i]) : (short)0;
            }
        } else {
            const short* ap = (const short*)Avp + abase;
            if (gk + 8 <= K) {
                i32x2 a = *(const i32x2*)ap;
                i32x2 b = *(const i32x2*)(ap + 4);
                *(i32x2*)&tmp[0] = a; *(i32x2*)&tmp[4] = b;
            } else {
#pragma unroll
                for (int i = 0; i < 8; ++i) tmp[i] = (gk + i < K) ? ap[i] : (short)0;
            }
        }
    };
    auto ldW = [&](int k0, short* tmp) {
        int gk = k0 + c4 * 8;
        if (gnW < N && gk + 8 <= K) {
            const short* wp = W + (size_t)gnW * K + gk;
            i32x2 a = *(const i32x2*)wp;
            i32x2 b = *(const i32x2*)(wp + 4);
            *(i32x2*)&tmp[0] = a; *(i32x2*)&tmp[4] = b;
        } else {
#pragma unroll
            for (int i = 0; i < 8; ++i)
                tmp[i] = (gnW < N && gk + i < K) ? W[(size_t)gnW * K + gk + i] : (short)0;
        }
    };

    // prologue: phase 0 into registers
    ldA(rowA0, 0, a0);
    ldA(rowA1, 0, a1);
    ldW(0, wv);

    int ph = 0;
    for (int k0 = 0; k0 < K; k0 += 32, ph ^= 1) {
        // write current phase to LDS buffer ph
        *(i32x4*)&As[ph][rowA0 * 40 + c4 * 8] = *(i32x4*)a0;
        *(i32x4*)&As[ph][rowA1 * 40 + c4 * 8] = *(i32x4*)a1;
        *(i32x4*)&Bs[ph][rowA0 * 40 + c4 * 8] = *(i32x4*)wv;
        // prefetch next phase into registers (in flight across the barrier)
        if (k0 + 32 < K) {
            ldA(rowA0, k0 + 32, a0);
            ldA(rowA1, k0 + 32, a1);
            ldW(k0 + 32, wv);
        }
        __syncthreads();

        bf16x8 af[4], bf[2];
#pragma unroll
        for (int mi = 0; mi < 4; ++mi) af[mi] = *(const bf16x8*)&As[ph][(wm + mi * 16 + l15) * 40 + h * 8];
#pragma unroll
        for (int nj = 0; nj < 2; ++nj) bf[nj] = *(const bf16x8*)&Bs[ph][(wn + nj * 16 + l15) * 40 + h * 8];
#pragma unroll
        for (int mi = 0; mi < 4; ++mi)
#pragma unroll
            for (int nj = 0; nj < 2; ++nj) {
                if (TROUT)
                    acc[mi][nj] = __builtin_amdgcn_mfma_f32_16x16x32_bf16(bf[nj], af[mi], acc[mi][nj], 0, 0, 0);
                else
                    acc[mi][nj] = __builtin_amdgcn_mfma_f32_16x16x32_bf16(af[mi], bf[nj], acc[mi][nj], 0, 0, 0);
            }
    }

    if (!TROUT) {
#pragma unroll
        for (int mi = 0; mi < 4; ++mi) {
#pragma unroll
            for (int nj = 0; nj < 2; ++nj) {
                int gn = bn + wn + nj * 16 + l15;
                if (gn < N) {
#pragma unroll
                    for (int r = 0; r < 4; ++r) {
                        int gm = bm + wm + mi * 16 + h * 4 + r;
                        float v = acc[mi][nj][r];
                        size_t oi = (size_t)gm * N + gn;
                        if (OUTBF16)      ((short*)outp)[oi] = (short)f2b(v);
                        else if (ADD)     ((float*)outp)[oi] += v;
                        else              ((float*)outp)[oi] = v;
                    }
                }
            }
        }
    } else {
#pragma unroll
        for (int mi = 0; mi < 4; ++mi) {
            int gm = bm + wm + mi * 16 + l15;
#pragma unroll
            for (int nj = 0; nj < 2; ++nj)
#pragma unroll
                for (int r = 0; r < 4; ++r) {
                    int gn = bn + wn + nj * 16 + h * 4 + r;
                    if (gn < N) ((float*)outp)[(size_t)gn * M + gm] = acc[mi][nj][r];
                }
        }
    }
}

// ---------------------------------------------------------------------------
// LayerNorm D=128, fp32 in -> bf16 out.
// ---------------------------------------------------------------------------
__global__ __launch_bounds__(256) void ln_k(const float* __restrict__ in,
                                            const float* __restrict__ w,
                                            const float* __restrict__ b,
                                            short* __restrict__ out) {
    int t = blockIdx.x * 4 + (threadIdx.x >> 6);
    int lane = threadIdx.x & 63;
    float2 v = *(const float2*)(in + (size_t)t * 128 + lane * 2);
    float s = v.x + v.y, sq = v.x * v.x + v.y * v.y;
#pragma unroll
    for (int off = 32; off > 0; off >>= 1) { s += __shfl_xor(s, off); sq += __shfl_xor(sq, off); }
    float mean = s * (1.f / 128.f);
    float var = sq * (1.f / 128.f) - mean * mean;
    float rstd = rsqrtf(var + 1e-5f);
    float2 wv = *(const float2*)(w + lane * 2);
    float2 bv = *(const float2*)(b + lane * 2);
    float ox = (v.x - mean) * rstd * wv.x + bv.x;
    float oy = (v.y - mean) * rstd * wv.y + bv.y;
    ((unsigned*)out)[(size_t)t * 64 + lane] = f2b(ox) | ((unsigned)f2b(oy) << 16);
}

// ---------------------------------------------------------------------------
// Fused qkv depthwise 3x3 + l2norm(q,k heads).
// ---------------------------------------------------------------------------
__global__ __launch_bounds__(256) void dwl2n_k(const short* __restrict__ in,
                                               const float* __restrict__ wqT,
                                               short* __restrict__ out) {
    int idx = blockIdx.x * 256 + threadIdx.x;    // < M*48
    int q = idx % 48;
    int t = idx / 48;
    int c0 = q * 8;
    int l = t & 1023, n = t >> 10;
    int y = l >> 5, x = l & 31;
    int tb = n << 10;

    float acc[8];
#pragma unroll
    for (int k = 0; k < 8; ++k) acc[k] = 0.f;

#pragma unroll
    for (int i = 0; i < 3; ++i) {
        int yy = y + i - 1;
        if (yy < 0 || yy >= 32) continue;
#pragma unroll
        for (int j = 0; j < 3; ++j) {
            int xx = x + j - 1;
            if (xx < 0 || xx >= 32) continue;
            bf16x8 d = *(const bf16x8*)(in + (size_t)(tb + (yy << 5) + xx) * 384 + c0);
            float4 wa = *(const float4*)(wqT + (i * 3 + j) * 384 + c0);
            float4 wb = *(const float4*)(wqT + (i * 3 + j) * 384 + c0 + 4);
            acc[0] += b2f((unsigned short)d[0]) * wa.x;
            acc[1] += b2f((unsigned short)d[1]) * wa.y;
            acc[2] += b2f((unsigned short)d[2]) * wa.z;
            acc[3] += b2f((unsigned short)d[3]) * wa.w;
            acc[4] += b2f((unsigned short)d[4]) * wb.x;
            acc[5] += b2f((unsigned short)d[5]) * wb.y;
            acc[6] += b2f((unsigned short)d[6]) * wb.z;
            acc[7] += b2f((unsigned short)d[7]) * wb.w;
        }
    }
    float ss = 0.f;
#pragma unroll
    for (int k = 0; k < 8; ++k) ss += acc[k] * acc[k];
    ss += __shfl_xor(ss, 1);
    ss += __shfl_xor(ss, 2);
    float sc = (c0 < 256) ? (1.f / fmaxf(sqrtf(ss), 1e-12f)) : 1.f;
    unsigned o[4];
#pragma unroll
    for (int k = 0; k < 4; ++k)
        o[k] = f2b(acc[2 * k] * sc) | ((unsigned)f2b(acc[2 * k + 1] * sc) << 16);
    *(i32x4*)(out + (size_t)t * 384 + c0) = *(i32x4*)o;
}

// ---------------------------------------------------------------------------
// Fused GDFN depthwise (round-5 version, out lda = 344).
// ---------------------------------------------------------------------------
__global__ __launch_bounds__(256) void gdfn2_k(const short* __restrict__ in,
                                               const float* __restrict__ wgT,
                                               short* __restrict__ out) {
    int idx = blockIdx.x * 256 + threadIdx.x;    // < M*43
    int q = idx % 43;
    int t = idx / 43;
    int c0 = q * 8;
    int l = t & 1023, n = t >> 10;
    int y = l >> 5, x = l & 31;
    int tb = n << 10;

    float a[8], g[8];
#pragma unroll
    for (int k = 0; k < 8; ++k) { a[k] = 0.f; g[k] = 0.f; }

#pragma unroll
    for (int i = 0; i < 3; ++i) {
        int yy = y + i - 1;
        if (yy < 0 || yy >= 32) continue;
#pragma unroll
        for (int j = 0; j < 3; ++j) {
            int xx = x + j - 1;
            if (xx < 0 || xx >= 32) continue;
            const short* p = in + (size_t)(tb + (yy << 5) + xx) * 680 + c0;
            bf16x8 d1 = *(const bf16x8*)p;
            i32x2 d2a = *(const i32x2*)(p + 340);
            i32x2 d2b = *(const i32x2*)(p + 344);
            short d2[8];
            *(i32x2*)&d2[0] = d2a; *(i32x2*)&d2[4] = d2b;
            const float* wp = wgT + (i * 3 + j) * 680 + c0;
            float4 w1a = *(const float4*)wp;
            float4 w1b = *(const float4*)(wp + 4);
            float w1[8] = {w1a.x, w1a.y, w1a.z, w1a.w, w1b.x, w1b.y, w1b.z, w1b.w};
            float w2[8];
#pragma unroll
            for (int k = 0; k < 8; ++k) w2[k] = wp[340 + k];
#pragma unroll
            for (int k = 0; k < 8; ++k) {
                a[k] += b2f((unsigned short)d1[k]) * w1[k];
                g[k] += b2f((unsigned short)d2[k]) * w2[k];
            }
        }
    }
    unsigned o[4];
#pragma unroll
    for (int k = 0; k < 4; ++k) {
        float r0 = 0.5f * a[2 * k] * (1.f + erff(a[2 * k] * 0.70710678118f)) * g[2 * k];
        float r1 = 0.5f * a[2 * k + 1] * (1.f + erff(a[2 * k + 1] * 0.70710678118f)) * g[2 * k + 1];
        o[k] = f2b(r0) | ((unsigned)f2b(r1) << 16);
    }
    short* op = out + (size_t)t * 344 + c0;
    if (q < 42) *(i32x4*)op = *(i32x4*)o;
    else        *(i32x2*)op = (i32x2){(int)o[0], (int)o[1]};
}

// ---------------------------------------------------------------------------
// MFMA flash attention v5 (round-10 version, verbatim — PROVEN at 49.2us):
// 64 q-rows/block x 1600 blocks, LDS K+Vp double-buffer, one barrier/tile,
// register prefetch, zero-shuffle PV, fixed-bound softmax.
// ---------------------------------------------------------------------------
__global__ __launch_bounds__(256) void attn_k(const short* __restrict__ qkv,
                                              const float* __restrict__ temp,
                                              short* __restrict__ outp) {
    __shared__ __align__(16) short Ks[2][64 * 40];
    __shared__ __align__(16) short Vp[2][2048];
    const int bid = blockIdx.x;              // 1600 = nh*16 + qt
    const int qt = bid & 15, nh = bid >> 4;
    const int hd = nh & 3, n = nh >> 2;
    const int tid = threadIdx.x;
    const int w = tid >> 6, lane = tid & 63;
    const int h = lane >> 4, l15 = lane & 15;
    const size_t base = (size_t)n * 1024 * 384;
    const int qrow = qt * 64 + w * 16 + l15;
    const float ts2 = temp[hd] * 1.44269504089f;       // exp2-domain temperature
    const float nbound = -(fabsf(ts2) + 0.25f);        // static softmax shift

    bf16x8 qf = *(const bf16x8*)(qkv + base + (size_t)qrow * 384 + hd * 32 + h * 8);
    f32x4 o0 = {0.f,0.f,0.f,0.f}, o1 = {0.f,0.f,0.f,0.f};
    float ps = 0.f;

    const int skey = tid >> 2, sc4 = tid & 3;
    const int sg = skey >> 5, skey5 = skey & 31;
    const int sh = (skey5 >> 2) & 3;
    const int sj = (skey5 & 3) + ((skey5 >> 4) << 2);
    const int sgran0 = (sg * 4 + sh) * 32 + sc4 * 8;
    const short* kbase = qkv + base + (size_t)skey * 384 + 128 + hd * 32 + sc4 * 8;

    i32x4 kreg = *(const i32x4*)kbase;
    i32x4 vreg = *(const i32x4*)(kbase + 128);

    for (int t = 0; t < 16; ++t) {
        const int nb = t & 1;
        *(i32x4*)&Ks[nb][skey * 40 + sc4 * 8] = kreg;
        {
            short vs[8];
            *(i32x4*)vs = vreg;
#pragma unroll
            for (int i = 0; i < 8; ++i) {
                int gran = sgran0 + i;
                gran ^= (gran >> 3) & 7;
                Vp[nb][gran * 8 + sj] = vs[i];
            }
        }
        if (t < 15) {
            const short* kp = kbase + (size_t)(t + 1) * 64 * 384;
            kreg = *(const i32x4*)kp;
            vreg = *(const i32x4*)(kp + 128);
        }
        __syncthreads();

        const bf16x8 kf0 = *(const bf16x8*)&Ks[nb][l15 * 40 + h * 8];
        const bf16x8 kf1 = *(const bf16x8*)&Ks[nb][(16 + l15) * 40 + h * 8];
        const bf16x8 kf2 = *(const bf16x8*)&Ks[nb][(32 + l15) * 40 + h * 8];
        const bf16x8 kf3 = *(const bf16x8*)&Ks[nb][(48 + l15) * 40 + h * 8];
        int gr0 = h * 32 + l15;            gr0 ^= (gr0 >> 3) & 7;
        int gr1 = h * 32 + 16 + l15;       gr1 ^= (gr1 >> 3) & 7;
        int gr2 = (4 + h) * 32 + l15;      gr2 ^= (gr2 >> 3) & 7;
        int gr3 = (4 + h) * 32 + 16 + l15; gr3 ^= (gr3 >> 3) & 7;
        const bf16x8 va0 = *(const bf16x8*)&Vp[nb][gr0 * 8];
        const bf16x8 va1 = *(const bf16x8*)&Vp[nb][gr1 * 8];
        const bf16x8 vb0 = *(const bf16x8*)&Vp[nb][gr2 * 8];
        const bf16x8 vb1 = *(const bf16x8*)&Vp[nb][gr3 * 8];
        const f32x4 z = {0.f, 0.f, 0.f, 0.f};

        f32x4 s0 = __builtin_amdgcn_mfma_f32_16x16x32_bf16(kf0, qf, z, 0, 0, 0);
        f32x4 s1 = __builtin_amdgcn_mfma_f32_16x16x32_bf16(kf1, qf, z, 0, 0, 0);
        f32x4 s2 = __builtin_amdgcn_mfma_f32_16x16x32_bf16(kf2, qf, z, 0, 0, 0);
        f32x4 s3 = __builtin_amdgcn_mfma_f32_16x16x32_bf16(kf3, qf, z, 0, 0, 0);
        float p[16];
#pragma unroll
        for (int r = 0; r < 4; ++r) {
            p[r]      = exp2f(fmaf(s0[r], ts2, nbound));
            p[4 + r]  = exp2f(fmaf(s1[r], ts2, nbound));
            p[8 + r]  = exp2f(fmaf(s2[r], ts2, nbound));
            p[12 + r] = exp2f(fmaf(s3[r], ts2, nbound));
        }
#pragma unroll
        for (int r = 0; r < 16; ++r) ps += p[r];
        union { unsigned u[4]; bf16x8 v; } pf1, pf2;
#pragma unroll
        for (int r = 0; r < 4; ++r) {
            pf1.u[r] = cvtpk(p[2 * r], p[2 * r + 1]);
            pf2.u[r] = cvtpk(p[8 + 2 * r], p[8 + 2 * r + 1]);
        }
        o0 = __builtin_amdgcn_mfma_f32_16x16x32_bf16(va0, pf1.v, o0, 0, 0, 0);
        o1 = __builtin_amdgcn_mfma_f32_16x16x32_bf16(va1, pf1.v, o1, 0, 0, 0);
        o0 = __builtin_amdgcn_mfma_f32_16x16x32_bf16(vb0, pf2.v, o0, 0, 0, 0);
        o1 = __builtin_amdgcn_mfma_f32_16x16x32_bf16(vb1, pf2.v, o1, 0, 0, 0);
    }

    ps += __shfl_xor(ps, 16);
    ps += __shfl_xor(ps, 32);
    float inv = 1.f / ps;

    size_t ob = ((size_t)n * 1024 + qrow) * 128 + hd * 32;
    unsigned u;
    u = f2b(o0[0] * inv) | ((unsigned)f2b(o0[1] * inv) << 16); *(unsigned*)(outp + ob + h * 4) = u;
    u = f2b(o0[2] * inv) | ((unsigned)f2b(o0[3] * inv) << 16); *(unsigned*)(outp + ob + h * 4 + 2) = u;
    u = f2b(o1[0] * inv) | ((unsigned)f2b(o1[1] * inv) << 16); *(unsigned*)(outp + ob + 16 + h * 4) = u;
    u = f2b(o1[2] * inv) | ((unsigned)f2b(o1[3] * inv) << 16); *(unsigned*)(outp + ob + 16 + h * 4 + 2) = u;
}

// ---------------------------------------------------------------------------
extern "C" void kernel_launch(void* const* d_in, const int* in_sizes, int n_in,
                              void* d_out, int out_size, void* d_ws, size_t ws_size,
                              hipStream_t stream) {
    const float* buffer      = (const float*)d_in[0];
    const float* mlp_w       = (const float*)d_in[1];
    const float* ln_attn_w   = (const float*)d_in[2];
    const float* ln_attn_b   = (const float*)d_in[3];
    const float* ln_ffn_w    = (const float*)d_in[4];
    const float* ln_ffn_b    = (const float*)d_in[5];
    const float* qkv_w       = (const float*)d_in[6];
    const float* qkv_dw_w    = (const float*)d_in[7];
    const float* temperature = (const float*)d_in[8];
    const float* proj_attn_w = (const float*)d_in[9];
    const float* ffn_in_w    = (const float*)d_in[10];
    const float* ffn_dw_w    = (const float*)d_in[11];
    const float* ffn_out_w   = (const float*)d_in[12];
    const float* proj3d_w    = (const float*)d_in[13];

    char* wsb = (char*)d_ws;
    short* Wbf     = (short*)wsb;                 // 286208 bf16 weights (round-5 layout)
    short* mlpW    = Wbf;                         // [128][640]
    short* qkvW    = Wbf + 81920;                 // [384][128]
    short* projW   = Wbf + 131072;                // [128][128]
    short* ffnInW  = Wbf + 147456;                // [680][128]
    short* ffnOutW = Wbf + 234496;                // [128][340]
    short* p3dW    = Wbf + 278016;                // [64][128]
    float* wqT     = (float*)(wsb + 573440);      // [9][384] f32
    float* wgT     = (float*)(wsb + 587264);      // [9][680] f32
    short* PatchB  = (short*)(wsb + 611840);      // [M][640] bf16
    float* tok     = (float*)(wsb + 33379840);    // [M][128] f32
    short* LNbf    = (short*)(wsb + 46487040);    // [M][128] bf16
    short* QKVpre  = (short*)(wsb + 53040640);    // [M][384] bf16
    short* qkvb    = (short*)(wsb + 72701440);    // [M][384] bf16
    short* AObf    = (short*)(wsb + 92362240);    // [M][128] bf16
    short* F1      = (short*)(wsb + 98915840);    // [M][680] bf16
    short* G       = (short*)(wsb + 133731840);   // [M][344] bf16 (lda 344)

    dim3 blk(256);

    prep_k<<<1156, blk, 0, stream>>>(mlp_w, qkv_w, proj_attn_w, ffn_in_w, ffn_out_w, proj3d_w,
                                     qkv_dw_w, ffn_dw_w, Wbf, wqT, wgT);
    unfold_k<<<6400, blk, 0, stream>>>(buffer, PatchB);

    // S2T: tok = patches @ mlp_w^T (f32 out), K padded to 640
    mm_k<false, false, false, false><<<dim3(200, 2), blk, 0, stream>>>(PatchB, mlpW, tok, M_TOK, 128, 640, 640);
    ln_k<<<6400, blk, 0, stream>>>(tok, ln_attn_w, ln_attn_b, LNbf);
    // qkv 1x1 (bf16 out)
    mm_k<false, false, true, false><<<dim3(200, 6), blk, 0, stream>>>(LNbf, qkvW, QKVpre, M_TOK, 384, 128, 128);
    // fused dwconv + l2norm
    dwl2n_k<<<4800, blk, 0, stream>>>(QKVpre, wqT, qkvb);
    // attention (v5: 64 q-rows/block, 1600 blocks)
    attn_k<<<1600, blk, 0, stream>>>(qkvb, temperature, AObf);
    // proj + residual
    mm_k<true, false, false, false><<<dim3(200, 2), blk, 0, stream>>>(AObf, projW, tok, M_TOK, 128, 128, 128);
    ln_k<<<6400, blk, 0, stream>>>(tok, ln_ffn_w, ln_ffn_b, LNbf);
    // ffn_in 1x1 (bf16 out)
    mm_k<false, false, true, false><<<dim3(200, 11), blk, 0, stream>>>(LNbf, ffnInW, F1, M_TOK, 680, 128, 128);
    // fused GDFN dwconv + gelu gate
    gdfn2_k<<<4300, blk, 0, stream>>>(F1, wgT, G);
    // ffn_out + residual (A lda = 344)
    mm_k<true, false, false, false><<<dim3(200, 2), blk, 0, stream>>>(G, ffnOutW, tok, M_TOK, 128, 340, 344);
    // Token2SAI (transposed product, coalesced)
    mm_k<false, true, false, true><<<dim3(200, 1), blk, 0, stream>>>(tok, p3dW, d_out, M_TOK, 64, 128, 128);
}